// Round 9
// baseline (186.390 us; speedup 1.0000x reference)
//
#include <hip/hip_runtime.h>
#include <hip/hip_bf16.h>

// Fused: QKV proj (+bias) -> RoPE(Q,K) -> MHA softmax -> out proj (+bias)
// B=8 S=1024 D=1024 H=16 Dk=64.
// GEMM engine (R9): identical geometry to R8 (BM=256 x BN=128, BK=32, 8 waves,
// 4Mx2N) but staging is REG-STAGED with T14 async split instead of
// global_load_lds: issue global->VGPR loads for tile j+2 at iter top (latency
// hidden under a full iter of MFMA), compute tile j from LDS (compiler
// schedules ds_read/MFMA interleave), then vmcnt(3) + ds_write tile j+1 into
// the just-freed slot + lgkmcnt(0) + barrier. 2 LDS slots (48KB). P/Q register
// sets are statically named (rule #20) and alternated via unroll-by-2.

typedef __bf16 bf16_t;
typedef __bf16 bf16x8 __attribute__((ext_vector_type(8)));
typedef float  f32x4  __attribute__((ext_vector_type(4)));

static __device__ __forceinline__ f32x4 mfma16(bf16x8 a, bf16x8 b, f32x4 c) {
  return __builtin_amdgcn_mfma_f32_16x16x32_bf16(a, b, c, 0, 0, 0);
}
static __device__ __forceinline__ void gload_lds16(const void* g, void* l) {
  __builtin_amdgcn_global_load_lds((const __attribute__((address_space(1))) void*)g,
                                   (__attribute__((address_space(3))) void*)l,
                                   16, 0, 0);
}
#define VMCNT(n) asm volatile("s_waitcnt vmcnt(" #n ")" ::: "memory")
#define VMCNT0() asm volatile("s_waitcnt vmcnt(0)" ::: "memory")
#define BAR() __builtin_amdgcn_s_barrier()
#define LGKMBAR() do { asm volatile("s_waitcnt lgkmcnt(0)" ::: "memory"); \
                       __builtin_amdgcn_s_barrier(); \
                       __builtin_amdgcn_sched_barrier(0); } while (0)

#if __has_builtin(__builtin_amdgcn_exp2f)
#define EXP2F(x) __builtin_amdgcn_exp2f(x)
#else
#define EXP2F(x) exp2f(x)
#endif

// ---------------- prep kernels ----------------
__global__ void k_cast(const float* __restrict__ s, bf16_t* __restrict__ d, int n4) {
  int i = blockIdx.x * 256 + threadIdx.x;
  if (i >= n4) return;
  float4 v = reinterpret_cast<const float4*>(s)[i];
  union { bf16_t b[4]; unsigned long long u; } pk;
  pk.b[0] = (bf16_t)v.x; pk.b[1] = (bf16_t)v.y;
  pk.b[2] = (bf16_t)v.z; pk.b[3] = (bf16_t)v.w;
  reinterpret_cast<unsigned long long*>(d)[i] = pk.u;
}

__global__ void k_cast_w(const float* __restrict__ w0, const float* __restrict__ w1,
                         const float* __restrict__ w2, const float* __restrict__ w3,
                         bf16_t* __restrict__ dst) {
  int z = blockIdx.y;
  const float* s = (z == 0) ? w0 : (z == 1) ? w1 : (z == 2) ? w2 : w3;
  int i = blockIdx.x * 256 + threadIdx.x;
  float4 v = reinterpret_cast<const float4*>(s)[i];
  union { bf16_t b[4]; unsigned long long u; } pk;
  pk.b[0] = (bf16_t)v.x; pk.b[1] = (bf16_t)v.y;
  pk.b[2] = (bf16_t)v.z; pk.b[3] = (bf16_t)v.w;
  reinterpret_cast<unsigned long long*>(dst + (size_t)z * 1048576)[i] = pk.u;
}

__global__ void k_rope_table(const int* __restrict__ pos, float2* __restrict__ rt) {
  int s = blockIdx.x * 8 + (threadIdx.x >> 5);
  int f = threadIdx.x & 31;
  float p = (float)pos[s];
  float inv = powf(10000.0f, -(float)(2 * f) / 64.0f);
  float a = p * inv;
  rt[s * 32 + f] = make_float2(cosf(a), sinf(a));
}

// ==== R9 GEMM body: BM=256, BN=128, BK=32, 32 K-tiles, reg-staged, 2 slots ====
// Slot (24576B): A 16KB = 16 groups x 1KB; B 8KB at +16384.
//   1KB group = 16 rows x 32 k, lane-ordered -> frag read = base + lane*16.
// Stage map (granule s_: A l*512+t, B s_=t): row=((s_>>6)<<4)|(s_&15),
//   koff=((s_>>4)&3)*8.  ds_write dst = slot + t*16 (+0/+8192 A, +16384 B):
//   contiguous per wave -> conflict-free.
// Race ledger (1 barrier/iter): iter j computes slot j&1 (reads retired before
//   its MFMAs, pre-barrier); iter j's ds_write targets slot (j+1)&1, last read
//   in iter j-1 before barrier(j-1) -> no WAR. vmcnt(3) before the write waits
//   the held set (issued one full iter earlier), leaving the newest 3 in
//   flight. lgkmcnt(0) before barrier publishes the ds_writes block-wide.
#define GEMM_R9_BODY(Aptr, Bptr)                                               \
  __shared__ alignas(16) char LDSbuf[49152];                                   \
  const int t = threadIdx.x;                                                   \
  const int lane = t & 63, w = t >> 6;                                         \
  const int hi = lane >> 4, c = lane & 15;                                     \
  const int wm4 = w >> 1, wn2 = w & 1;                                         \
  const bf16_t* gA0;                                                           \
  const bf16_t* gA1;                                                           \
  {                                                                            \
    int s0 = t, s1 = 512 + t;                                                  \
    gA0 = (Aptr) + (size_t)(i0 + ((s0 >> 6) << 4) + (s0 & 15)) * 1024 +        \
          ((s0 >> 4) & 3) * 8;                                                 \
    gA1 = (Aptr) + (size_t)(i0 + ((s1 >> 6) << 4) + (s1 & 15)) * 1024 +        \
          ((s1 >> 4) & 3) * 8;                                                 \
  }                                                                            \
  const bf16_t* gB = (Bptr) + (size_t)(e0 + ((t >> 6) << 4) + (t & 15)) * 1024 \
                     + ((t >> 4) & 3) * 8;                                     \
  char* const wdst = LDSbuf + t * 16;                                          \
  bf16x8 PA0, PA1, PB0, QA0, QA1, QB0;                                         \
  auto loadP = [&](int kt) {                                                   \
    PA0 = *(const bf16x8*)(gA0 + kt * 32);                                     \
    PA1 = *(const bf16x8*)(gA1 + kt * 32);                                     \
    PB0 = *(const bf16x8*)(gB + kt * 32);                                      \
    __builtin_amdgcn_sched_barrier(0);                                         \
  };                                                                           \
  auto loadQ = [&](int kt) {                                                   \
    QA0 = *(const bf16x8*)(gA0 + kt * 32);                                     \
    QA1 = *(const bf16x8*)(gA1 + kt * 32);                                     \
    QB0 = *(const bf16x8*)(gB + kt * 32);                                      \
    __builtin_amdgcn_sched_barrier(0);                                         \
  };                                                                           \
  auto writeP = [&](int slot) {                                                \
    *(bf16x8*)(wdst + slot * 24576) = PA0;                                     \
    *(bf16x8*)(wdst + slot * 24576 + 8192) = PA1;                              \
    *(bf16x8*)(wdst + slot * 24576 + 16384) = PB0;                             \
  };                                                                           \
  auto writeQ = [&](int slot) {                                                \
    *(bf16x8*)(wdst + slot * 24576) = QA0;                                     \
    *(bf16x8*)(wdst + slot * 24576 + 8192) = QA1;                              \
    *(bf16x8*)(wdst + slot * 24576 + 16384) = QB0;                             \
  };                                                                           \
  f32x4 acc[4][4] = {};                                                        \
  const char* laB = LDSbuf + wm4 * 4096 + lane * 16;                           \
  const char* lbB = LDSbuf + 16384 + wn2 * 4096 + lane * 16;                   \
  auto compute = [&](int slot) {                                               \
    const char* la = laB + slot * 24576;                                       \
    const char* lb = lbB + slot * 24576;                                       \
    bf16x8 af[4], bg[4];                                                       \
    _Pragma("unroll") for (int fr = 0; fr < 4; ++fr)                           \
      af[fr] = *(const bf16x8*)(la + fr * 1024);                               \
    _Pragma("unroll") for (int nc = 0; nc < 4; ++nc)                           \
      bg[nc] = *(const bf16x8*)(lb + nc * 1024);                               \
    _Pragma("unroll") for (int fr = 0; fr < 4; ++fr)                           \
      _Pragma("unroll") for (int nc = 0; nc < 4; ++nc)                         \
        acc[fr][nc] = mfma16(af[fr], bg[nc], acc[fr][nc]);                     \
  };                                                                           \
  loadP(0);                                                                    \
  loadQ(1);                                                                    \
  VMCNT(3);                                                                    \
  writeP(0);                                                                   \
  LGKMBAR();                                                                   \
  for (int jj = 0; jj < 15; ++jj) {                                            \
    loadP(jj * 2 + 2);      /* tile j+2 into P (slot0-bound, even) */          \
    compute(0);             /* tile j (even -> slot0) */                       \
    VMCNT(3);               /* Q (tile j+1) resident; P stays in flight */     \
    writeQ(1);                                                                 \
    LGKMBAR();                                                                 \
    loadQ(jj * 2 + 3);      /* tile j+3 into Q */                              \
    compute(1);             /* tile j+1 (odd -> slot1) */                      \
    VMCNT(3);               /* P (tile j+2) resident */                        \
    writeP(0);                                                                 \
    LGKMBAR();                                                                 \
  }                                                                            \
  compute(0);               /* tile 30 */                                      \
  VMCNT0();                 /* Q = tile 31 resident */                         \
  writeQ(1);                                                                   \
  LGKMBAR();                                                                   \
  compute(1);               /* tile 31 */

// ---------------- fused QKV GEMM: N=3072 (Wq|Wk|Wv concat) ----------------
// 768 blocks = 32 m (fastest) x 24 n (R8's proven order, FETCH 45MB).
__global__ __launch_bounds__(512) void k_gemm_qkv(
    const bf16_t* __restrict__ Xb, const bf16_t* __restrict__ Wqkv,
    const float* __restrict__ bq, const float* __restrict__ bk,
    const float* __restrict__ bv, const float2* __restrict__ rt,
    bf16_t* __restrict__ Qh, bf16_t* __restrict__ Kh, bf16_t* __restrict__ Vt) {
  const int bid = blockIdx.x;
  const int i0 = (bid & 31) * 256;
  const int e0 = (bid >> 5) * 128;

  GEMM_R9_BODY(Xb, Wqkv)

  // Epilogue: one head per wave (64-col window at ez0).
  const int z = e0 >> 10;                       // 0:Q 1:K 2:V
  const int ez0 = (e0 & 1023) + wn2 * 64;       // multiple of 64
  const int h = ez0 >> 6;
  const float* bias = (z == 0) ? bq : (z == 1) ? bk : bv;
  if (z == 2) {
#pragma unroll
    for (int fr = 0; fr < 4; ++fr) {
      int i = i0 + wm4 * 64 + fr * 16 + hi * 4;
      int b_ = i >> 10, s = i & 1023;
#pragma unroll
      for (int nc = 0; nc < 4; ++nc) {
        int dk = nc * 16 + c;
        float bv_ = bias[ez0 + dk];
        union { bf16_t b[4]; unsigned long long u; } pk;
#pragma unroll
        for (int r = 0; r < 4; ++r) pk.b[r] = (bf16_t)(acc[fr][nc][r] + bv_);
        __builtin_memcpy(&Vt[((size_t)((b_ * 16 + h) * 64 + dk)) * 1024 + s], pk.b, 8);
      }
    }
  } else {
    bf16_t* O = (z == 0) ? Qh : Kh;
    // Q folds 1/sqrt(64) * log2(e): attn softmax runs in exp2 domain.
    const float scl = (z == 0) ? 0.18033688011112042f : 1.0f;
#pragma unroll
    for (int fr = 0; fr < 4; ++fr) {
      int i = i0 + wm4 * 64 + fr * 16 + hi * 4;
      int b_ = i >> 10, sbase = i & 1023;
      size_t obase = (size_t)((b_ * 16 + h) * 1024);
#pragma unroll
      for (int nc = 0; nc < 2; ++nc) {          // f<32; partner f+32 = frag nc+2
        int f = nc * 16 + c;
        float b1_ = bias[ez0 + f], b2_ = bias[ez0 + f + 32];
#pragma unroll
        for (int r = 0; r < 4; ++r) {
          int s = sbase + r;
          float2 cs = rt[s * 32 + f];
          float q1 = acc[fr][nc][r] + b1_;
          float q2 = acc[fr][nc + 2][r] + b2_;
          O[(obase + s) * 64 + f] = (bf16_t)((q1 * cs.x - q2 * cs.y) * scl);
          O[(obase + s) * 64 + f + 32] = (bf16_t)((q1 * cs.y + q2 * cs.x) * scl);
        }
      }
    }
  }
}

// ---------------- out projection (same engine): 256 blocks = 32m x 8n ------
__global__ __launch_bounds__(512) void k_gemm_out(
    const bf16_t* __restrict__ Og, const bf16_t* __restrict__ Wob,
    const float* __restrict__ bo, float* __restrict__ out) {
  const int bid = blockIdx.x;
  const int i0 = (bid & 31) * 256;
  const int e0 = (bid >> 5) * 128;

  GEMM_R9_BODY(Og, Wob)

#pragma unroll
  for (int fr = 0; fr < 4; ++fr) {
    int i = i0 + wm4 * 64 + fr * 16 + hi * 4;
#pragma unroll
    for (int nc = 0; nc < 4; ++nc) {
      int e = e0 + wn2 * 64 + nc * 16 + c;
      float bv_ = bo[e];
#pragma unroll
      for (int r = 0; r < 4; ++r)
        out[(size_t)(i + r) * 1024 + e] = acc[fr][nc][r] + bv_;
    }
  }
}

// ---------------- flash attention (R5, verified) ----------------
__global__ __launch_bounds__(512) void k_attn(
    const bf16_t* __restrict__ Qh, const bf16_t* __restrict__ Kh,
    const bf16_t* __restrict__ Vt, bf16_t* __restrict__ Og) {
  __shared__ alignas(16) char KL[3][8192];
  __shared__ alignas(16) char VL[3][8192];
  __shared__ alignas(16) char PL[8][2048];
  const int t = threadIdx.x;
  const int lane = t & 63, w = t >> 6;
  const int hi = lane >> 4, c = lane & 15;
  const int bid = blockIdx.x;
  const int wg = (bid & 7) * 128 + (bid >> 3);
  const int bh = wg >> 3, qt = wg & 7;
  const size_t base = (size_t)bh * 64 * 1024;
  const int q0 = qt * 128 + w * 16;

  const int sc = t & 15, sks = (t >> 4) & 7, sfr = t >> 7;
  const bf16_t* srcK = Kh + base + (size_t)(sfr * 16 + sc) * 64 + sks * 8;
  const bf16_t* srcV = Vt + base + (size_t)(sfr * 16 + sc) * 1024 + sks * 8;
  auto stage = [&](int b3, int kt) {
    gload_lds16(srcK + (size_t)kt * 64 * 64, &KL[b3][0] + t * 16);
    gload_lds16(srcV + kt * 64, &VL[b3][0] + t * 16);
  };

  bf16x8 qf[2];
  qf[0] = *(const bf16x8*)&Qh[base + (size_t)(q0 + c) * 64 + hi * 8];
  qf[1] = *(const bf16x8*)&Qh[base + (size_t)(q0 + c) * 64 + 32 + hi * 8];

  f32x4 o[4] = {};
  float m = -1e30f, lsum = 0.f;

  stage(0, 0);
  stage(1, 1);
  VMCNT(2);
  BAR();

  char* const plw = &PL[w][0];
  for (int kt = 0; kt < 16; ++kt) {
    const int b3 = kt % 3;
    if (kt + 2 < 16) stage((kt + 2) % 3, kt + 2);

    const char* kb = &KL[b3][0] + lane * 16;
    f32x4 st[4] = {};
#pragma unroll
    for (int ni = 0; ni < 4; ++ni)
#pragma unroll
      for (int kk = 0; kk < 2; ++kk)
        st[ni] = mfma16(*(const bf16x8*)(kb + ni * 2048 + kk * 1024), qf[kk], st[ni]);

    float pmax = -1e30f;
#pragma unroll
    for (int ni = 0; ni < 4; ++ni)
#pragma unroll
      for (int r = 0; r < 4; ++r) pmax = fmaxf(pmax, st[ni][r]);
    pmax = fmaxf(pmax, __shfl_xor(pmax, 16));
    pmax = fmaxf(pmax, __shfl_xor(pmax, 32));
    float mn = fmaxf(m, pmax);
    float scale = EXP2F(m - mn);
    m = mn;
    float psum = 0.f;
#pragma unroll
    for (int ni = 0; ni < 4; ++ni) {
      union { bf16_t b[4]; unsigned long long u; } pk;
#pragma unroll
      for (int r = 0; r < 4; ++r) {
        float p = EXP2F(st[ni][r] - mn);
        psum += p;
        pk.b[r] = (bf16_t)p;
      }
      __builtin_memcpy(plw + (ni * 2 + (hi >> 1)) * 256 + c * 16 + (hi & 1) * 8,
                       pk.b, 8);
    }
    psum += __shfl_xor(psum, 16);
    psum += __shfl_xor(psum, 32);
    lsum = lsum * scale + psum;
#pragma unroll
    for (int od = 0; od < 4; ++od)
#pragma unroll
      for (int r = 0; r < 4; ++r) o[od][r] *= scale;

    const char* vb = &VL[b3][0] + lane * 16;
#pragma unroll
    for (int od = 0; od < 4; ++od)
#pragma unroll
      for (int kk = 0; kk < 2; ++kk) {
        bf16x8 vf = *(const bf16x8*)(vb + od * 2048 + kk * 1024);
        bf16x8 pa = *(const bf16x8*)(plw + kk * 1024 + lane * 16);
        o[od] = mfma16(vf, pa, o[od]);
      }

    if (kt < 14) { VMCNT(2); } else if (kt == 14) { VMCNT0(); }
    if (kt < 15) { __builtin_amdgcn_sched_barrier(0); BAR(); __builtin_amdgcn_sched_barrier(0); }
  }

  float invl = 1.0f / lsum;
  int b_ = bh >> 4, h = bh & 15;
  size_t rowoff = ((size_t)(b_ * 1024 + q0 + c)) * 1024 + h * 64;
#pragma unroll
  for (int od = 0; od < 4; ++od) {
    union { bf16_t b[4]; unsigned long long u; } pk;
#pragma unroll
    for (int r = 0; r < 4; ++r) pk.b[r] = (bf16_t)(o[od][r] * invl);
    __builtin_memcpy(&Og[rowoff + od * 16 + hi * 4], pk.b, 8);
  }
}

extern "C" void kernel_launch(void* const* d_in, const int* in_sizes, int n_in,
                              void* d_out, int out_size, void* d_ws, size_t ws_size,
                              hipStream_t stream) {
  const float* x = (const float*)d_in[0];
  const int* pos = (const int*)d_in[1];
  const float* Wq = (const float*)d_in[2];
  const float* bq = (const float*)d_in[3];
  const float* Wk = (const float*)d_in[4];
  const float* bk = (const float*)d_in[5];
  const float* Wv = (const float*)d_in[6];
  const float* bv = (const float*)d_in[7];
  const float* Wo = (const float*)d_in[8];
  const float* bo = (const float*)d_in[9];
  float* out = (float*)d_out;

  // ws: [0,16M) Xb (reused as Og) | [16M,24M) Wqkv(6M)+Wob(2M) contiguous
  //     [24M,40M) Vt | [42M,..) rope table.  Q,K live in d_out (32MB).
  char* ws = (char*)d_ws;
  bf16_t* Xb = (bf16_t*)ws;
  bf16_t* Wqkv = (bf16_t*)(ws + (16u << 20));
  bf16_t* Wob = (bf16_t*)(ws + (22u << 20));
  bf16_t* Vt = (bf16_t*)(ws + (24u << 20));
  float2* rt = (float2*)(ws + (42u << 20));
  bf16_t* Qh = (bf16_t*)d_out;
  bf16_t* Kh = (bf16_t*)d_out + (size_t)8 * 1024 * 1024;
  bf16_t* Og = Xb;

  k_cast<<<8192, 256, 0, stream>>>(x, Xb, 8192 * 1024 / 4);
  k_cast_w<<<dim3(1024, 4), 256, 0, stream>>>(Wq, Wk, Wv, Wo, Wqkv);
  k_rope_table<<<128, 256, 0, stream>>>(pos, rt);

  k_gemm_qkv<<<768, 512, 0, stream>>>(Xb, Wqkv, bq, bk, bv, rt, Qh, Kh, Vt);
  k_attn<<<1024, 512, 0, stream>>>(Qh, Kh, Vt, Og);
  k_gemm_out<<<256, 512, 0, stream>>>(Og, Wob, bo, out);
}

// Round 10
// 174.252 us; speedup vs baseline: 1.0697x; 1.0697x over previous
//
#include <hip/hip_runtime.h>
#include <hip/hip_bf16.h>

// Fused: QKV proj (+bias) -> RoPE(Q,K) -> MHA softmax -> out proj (+bias)
// B=8 S=1024 D=1024 H=16 Dk=64.
// GEMM engine (R10): ZERO-LDS, ZERO-BARRIER direct-fragment GEMM.
// Operands are pre-swizzled in global memory into MFMA fragment-granule order:
//   granule g=(rg,kt,lane): 16B holding A[rg*16 + (lane&15)][kt*32+(lane>>4)*8 ..+8].
// Fragment load = one global_load_dwordx4 at base+lane*16 (coalesced, L2-hot).
// Each wave double-buffers its 8 fragment loads one iter ahead; no inter-wave
// sync at all. Rationale: R2-R9 (6 engines: 2-phase, 8-phase, deep-rotation,
// 3-blk/CU, compiler-scheduled, reg-staged) ALL pinned at ~23% MfmaUtil; the
// only shared mechanism was barrier-synced LDS round-trips. This removes them.

typedef __bf16 bf16_t;
typedef __bf16 bf16x8 __attribute__((ext_vector_type(8)));
typedef float  f32x4  __attribute__((ext_vector_type(4)));

static __device__ __forceinline__ f32x4 mfma16(bf16x8 a, bf16x8 b, f32x4 c) {
  return __builtin_amdgcn_mfma_f32_16x16x32_bf16(a, b, c, 0, 0, 0);
}
static __device__ __forceinline__ void gload_lds16(const void* g, void* l) {
  __builtin_amdgcn_global_load_lds((const __attribute__((address_space(1))) void*)g,
                                   (__attribute__((address_space(3))) void*)l,
                                   16, 0, 0);
}
#define VMCNT(n) asm volatile("s_waitcnt vmcnt(" #n ")" ::: "memory")
#define VMCNT0() asm volatile("s_waitcnt vmcnt(0)" ::: "memory")
#define BAR() __builtin_amdgcn_s_barrier()

#if __has_builtin(__builtin_amdgcn_exp2f)
#define EXP2F(x) __builtin_amdgcn_exp2f(x)
#else
#define EXP2F(x) exp2f(x)
#endif

// ---------------- prep: fragment-granule swizzle casts ----------------
// Layout: elem offset of granule (rg,kt,lane) = (rg*32 + kt)*512 + lane*8,
//   holding M[rg*16 + (lane&15)][kt*32 + (lane>>4)*8 .. +8) as bf16.
__global__ void k_cast_xf(const float* __restrict__ x, bf16_t* __restrict__ Xf) {
  int g = blockIdx.x * 256 + threadIdx.x;        // 1,048,576 granules (8192x1024)
  int rg = g >> 11, kt = (g >> 6) & 31, lane = g & 63;
  int m = rg * 16 + (lane & 15);
  int k = kt * 32 + (lane >> 4) * 8;
  const float* s = x + (size_t)m * 1024 + k;
  float4 v0 = *(const float4*)s;
  float4 v1 = *(const float4*)(s + 4);
  union { bf16_t b[8]; } pk;
  pk.b[0] = (bf16_t)v0.x; pk.b[1] = (bf16_t)v0.y; pk.b[2] = (bf16_t)v0.z; pk.b[3] = (bf16_t)v0.w;
  pk.b[4] = (bf16_t)v1.x; pk.b[5] = (bf16_t)v1.y; pk.b[6] = (bf16_t)v1.z; pk.b[7] = (bf16_t)v1.w;
  __builtin_memcpy(Xf + (size_t)g * 8, pk.b, 16);
}

// Wf rowgroups: [0,64) Wq | [64,128) Wk | [128,192) Wv | [192,256) Wo
__global__ void k_cast_wf(const float* __restrict__ Wq, const float* __restrict__ Wk,
                          const float* __restrict__ Wv, const float* __restrict__ Wo,
                          bf16_t* __restrict__ Wf) {
  int g = blockIdx.x * 256 + threadIdx.x;        // 524,288 granules (4096x1024)
  int rg = g >> 11, kt = (g >> 6) & 31, lane = g & 63;
  const float* src = (rg < 64) ? Wq : (rg < 128) ? Wk : (rg < 192) ? Wv : Wo;
  int row = (rg & 63) * 16 + (lane & 15);
  int k = kt * 32 + (lane >> 4) * 8;
  const float* s = src + (size_t)row * 1024 + k;
  float4 v0 = *(const float4*)s;
  float4 v1 = *(const float4*)(s + 4);
  union { bf16_t b[8]; } pk;
  pk.b[0] = (bf16_t)v0.x; pk.b[1] = (bf16_t)v0.y; pk.b[2] = (bf16_t)v0.z; pk.b[3] = (bf16_t)v0.w;
  pk.b[4] = (bf16_t)v1.x; pk.b[5] = (bf16_t)v1.y; pk.b[6] = (bf16_t)v1.z; pk.b[7] = (bf16_t)v1.w;
  __builtin_memcpy(Wf + (size_t)g * 8, pk.b, 16);
}

__global__ void k_rope_table(const int* __restrict__ pos, float2* __restrict__ rt) {
  int s = blockIdx.x * 8 + (threadIdx.x >> 5);
  int f = threadIdx.x & 31;
  float p = (float)pos[s];
  float inv = powf(10000.0f, -(float)(2 * f) / 64.0f);
  float a = p * inv;
  rt[s * 32 + f] = make_float2(cosf(a), sinf(a));
}

// ======= R10 direct-fragment GEMM body: 128x128 tile, 4 waves (2Mx2N) =======
// Per wave 64x64 (acc[4][4]); per iter (BK=32): 8 fragment loads (4 A, 4 B),
// 16 MFMA. Double-buffered sets P/Q (statically named, rule #20); loads for
// iter j+2 issue after set reuse; compiler handles vmcnt + WAR ordering.
#define GEMM_DIRECT_BODY(AfBase, BfBase)                                       \
  const int t = threadIdx.x;                                                   \
  const int lane = t & 63, w = t >> 6;                                         \
  const int hi = lane >> 4, c = lane & 15;                                     \
  const int wm = w >> 1, wn = w & 1;                                           \
  const bf16_t* Ab = (AfBase) + (size_t)((i0 >> 4) + wm * 4) * 16384 + lane * 8; \
  const bf16_t* Bb = (BfBase) + (size_t)((e0 >> 4) + wn * 4) * 16384 + lane * 8; \
  bf16x8 pa0, pa1, pa2, pa3, pb0, pb1, pb2, pb3;                               \
  bf16x8 qa0, qa1, qa2, qa3, qb0, qb1, qb2, qb3;                               \
  f32x4 acc[4][4] = {};                                                        \
  auto loadP = [&](int kt) {                                                   \
    pa0 = *(const bf16x8*)(Ab + kt * 512);                                     \
    pa1 = *(const bf16x8*)(Ab + 16384 + kt * 512);                             \
    pa2 = *(const bf16x8*)(Ab + 32768 + kt * 512);                             \
    pa3 = *(const bf16x8*)(Ab + 49152 + kt * 512);                             \
    pb0 = *(const bf16x8*)(Bb + kt * 512);                                     \
    pb1 = *(const bf16x8*)(Bb + 16384 + kt * 512);                             \
    pb2 = *(const bf16x8*)(Bb + 32768 + kt * 512);                             \
    pb3 = *(const bf16x8*)(Bb + 49152 + kt * 512);                             \
  };                                                                           \
  auto loadQ = [&](int kt) {                                                   \
    qa0 = *(const bf16x8*)(Ab + kt * 512);                                     \
    qa1 = *(const bf16x8*)(Ab + 16384 + kt * 512);                             \
    qa2 = *(const bf16x8*)(Ab + 32768 + kt * 512);                             \
    qa3 = *(const bf16x8*)(Ab + 49152 + kt * 512);                             \
    qb0 = *(const bf16x8*)(Bb + kt * 512);                                     \
    qb1 = *(const bf16x8*)(Bb + 16384 + kt * 512);                             \
    qb2 = *(const bf16x8*)(Bb + 32768 + kt * 512);                             \
    qb3 = *(const bf16x8*)(Bb + 49152 + kt * 512);                             \
  };                                                                           \
  auto compP = [&]() {                                                         \
    bf16x8 a_[4] = {pa0, pa1, pa2, pa3}, b_[4] = {pb0, pb1, pb2, pb3};         \
    _Pragma("unroll") for (int fr = 0; fr < 4; ++fr)                           \
      _Pragma("unroll") for (int nc = 0; nc < 4; ++nc)                         \
        acc[fr][nc] = mfma16(a_[fr], b_[nc], acc[fr][nc]);                     \
  };                                                                           \
  auto compQ = [&]() {                                                         \
    bf16x8 a_[4] = {qa0, qa1, qa2, qa3}, b_[4] = {qb0, qb1, qb2, qb3};         \
    _Pragma("unroll") for (int fr = 0; fr < 4; ++fr)                           \
      _Pragma("unroll") for (int nc = 0; nc < 4; ++nc)                         \
        acc[fr][nc] = mfma16(a_[fr], b_[nc], acc[fr][nc]);                     \
  };                                                                           \
  loadP(0);                                                                    \
  loadQ(1);                                                                    \
  _Pragma("unroll 3")                                                          \
  for (int jj = 0; jj < 15; ++jj) {                                            \
    compP(); loadP(jj * 2 + 2);                                                \
    compQ(); loadQ(jj * 2 + 3);                                                \
  }                                                                            \
  compP();                                                                     \
  compQ();

// ---------------- fused QKV GEMM: N=3072 (Wq|Wk|Wv concat) ----------------
// 1536 blocks = 64 m x 24 n (n-fastest: consecutive blocks share the A tile).
__global__ __launch_bounds__(256) void k_gemm_qkv(
    const bf16_t* __restrict__ Xf, const bf16_t* __restrict__ Wf,
    const float* __restrict__ bq, const float* __restrict__ bk,
    const float* __restrict__ bv, const float2* __restrict__ rt,
    bf16_t* __restrict__ Qh, bf16_t* __restrict__ Kh, bf16_t* __restrict__ Vt) {
  const int bid = blockIdx.x;
  const int i0 = (bid / 24) * 128;
  const int e0 = (bid % 24) * 128;

  GEMM_DIRECT_BODY(Xf, Wf)

  // Epilogue: one head per wave (64-col window at ez0).
  const int z = e0 >> 10;                       // 0:Q 1:K 2:V
  const int ez0 = (e0 & 1023) + wn * 64;        // multiple of 64
  const int h = ez0 >> 6;
  const float* bias = (z == 0) ? bq : (z == 1) ? bk : bv;
  if (z == 2) {
#pragma unroll
    for (int fr = 0; fr < 4; ++fr) {
      int i = i0 + wm * 64 + fr * 16 + hi * 4;
      int b_ = i >> 10, s = i & 1023;
#pragma unroll
      for (int nc = 0; nc < 4; ++nc) {
        int dk = nc * 16 + c;
        float bv_ = bias[ez0 + dk];
        union { bf16_t b[4]; } pk;
#pragma unroll
        for (int r = 0; r < 4; ++r) pk.b[r] = (bf16_t)(acc[fr][nc][r] + bv_);
        __builtin_memcpy(&Vt[((size_t)((b_ * 16 + h) * 64 + dk)) * 1024 + s], pk.b, 8);
      }
    }
  } else {
    bf16_t* O = (z == 0) ? Qh : Kh;
    // Q folds 1/sqrt(64) * log2(e): attn softmax runs in exp2 domain.
    const float scl = (z == 0) ? 0.18033688011112042f : 1.0f;
#pragma unroll
    for (int fr = 0; fr < 4; ++fr) {
      int i = i0 + wm * 64 + fr * 16 + hi * 4;
      int b_ = i >> 10, sbase = i & 1023;
      size_t obase = (size_t)((b_ * 16 + h) * 1024);
#pragma unroll
      for (int nc = 0; nc < 2; ++nc) {          // f<32; partner f+32 = frag nc+2
        int f = nc * 16 + c;
        float b1_ = bias[ez0 + f], b2_ = bias[ez0 + f + 32];
#pragma unroll
        for (int r = 0; r < 4; ++r) {
          int s = sbase + r;
          float2 cs = rt[s * 32 + f];
          float q1 = acc[fr][nc][r] + b1_;
          float q2 = acc[fr][nc + 2][r] + b2_;
          O[(obase + s) * 64 + f] = (bf16_t)((q1 * cs.x - q2 * cs.y) * scl);
          O[(obase + s) * 64 + f + 32] = (bf16_t)((q1 * cs.y + q2 * cs.x) * scl);
        }
      }
    }
  }
}

// ---------------- out projection: A = Ogf (granule layout), B = Wo rg 192+ --
// 512 blocks = 64 m x 8 n.
__global__ __launch_bounds__(256) void k_gemm_out(
    const bf16_t* __restrict__ Ogf, const bf16_t* __restrict__ Wf,
    const float* __restrict__ bo, float* __restrict__ out) {
  const int bid = blockIdx.x;
  const int i0 = (bid >> 3) * 128;
  const int e0 = (bid & 7) * 128;
  const bf16_t* WfO = Wf + (size_t)192 * 16384;

  GEMM_DIRECT_BODY(Ogf, WfO)

#pragma unroll
  for (int fr = 0; fr < 4; ++fr) {
    int i = i0 + wm * 64 + fr * 16 + hi * 4;
#pragma unroll
    for (int nc = 0; nc < 4; ++nc) {
      int e = e0 + wn * 64 + nc * 16 + c;
      float bv_ = bo[e];
#pragma unroll
      for (int r = 0; r < 4; ++r)
        out[(size_t)(i + r) * 1024 + e] = acc[fr][nc][r] + bv_;
    }
  }
}

// ---------------- flash attention (R5 engine; epilogue -> granule Ogf) ------
__global__ __launch_bounds__(512) void k_attn(
    const bf16_t* __restrict__ Qh, const bf16_t* __restrict__ Kh,
    const bf16_t* __restrict__ Vt, bf16_t* __restrict__ Ogf) {
  __shared__ alignas(16) char KL[3][8192];
  __shared__ alignas(16) char VL[3][8192];
  __shared__ alignas(16) char PL[8][2048];
  const int t = threadIdx.x;
  const int lane = t & 63, w = t >> 6;
  const int hi = lane >> 4, c = lane & 15;
  const int bid = blockIdx.x;
  const int wg = (bid & 7) * 128 + (bid >> 3);
  const int bh = wg >> 3, qt = wg & 7;
  const size_t base = (size_t)bh * 64 * 1024;
  const int q0 = qt * 128 + w * 16;

  const int sc = t & 15, sks = (t >> 4) & 7, sfr = t >> 7;
  const bf16_t* srcK = Kh + base + (size_t)(sfr * 16 + sc) * 64 + sks * 8;
  const bf16_t* srcV = Vt + base + (size_t)(sfr * 16 + sc) * 1024 + sks * 8;
  auto stage = [&](int b3, int kt) {
    gload_lds16(srcK + (size_t)kt * 64 * 64, &KL[b3][0] + t * 16);
    gload_lds16(srcV + kt * 64, &VL[b3][0] + t * 16);
  };

  bf16x8 qf[2];
  qf[0] = *(const bf16x8*)&Qh[base + (size_t)(q0 + c) * 64 + hi * 8];
  qf[1] = *(const bf16x8*)&Qh[base + (size_t)(q0 + c) * 64 + 32 + hi * 8];

  f32x4 o[4] = {};
  float m = -1e30f, lsum = 0.f;

  stage(0, 0);
  stage(1, 1);
  VMCNT(2);
  BAR();

  char* const plw = &PL[w][0];
  for (int kt = 0; kt < 16; ++kt) {
    const int b3 = kt % 3;
    if (kt + 2 < 16) stage((kt + 2) % 3, kt + 2);

    const char* kb = &KL[b3][0] + lane * 16;
    f32x4 st[4] = {};
#pragma unroll
    for (int ni = 0; ni < 4; ++ni)
#pragma unroll
      for (int kk = 0; kk < 2; ++kk)
        st[ni] = mfma16(*(const bf16x8*)(kb + ni * 2048 + kk * 1024), qf[kk], st[ni]);

    float pmax = -1e30f;
#pragma unroll
    for (int ni = 0; ni < 4; ++ni)
#pragma unroll
      for (int r = 0; r < 4; ++r) pmax = fmaxf(pmax, st[ni][r]);
    pmax = fmaxf(pmax, __shfl_xor(pmax, 16));
    pmax = fmaxf(pmax, __shfl_xor(pmax, 32));
    float mn = fmaxf(m, pmax);
    float scale = EXP2F(m - mn);
    m = mn;
    float psum = 0.f;
#pragma unroll
    for (int ni = 0; ni < 4; ++ni) {
      union { bf16_t b[4]; } pk;
#pragma unroll
      for (int r = 0; r < 4; ++r) {
        float p = EXP2F(st[ni][r] - mn);
        psum += p;
        pk.b[r] = (bf16_t)p;
      }
      __builtin_memcpy(plw + (ni * 2 + (hi >> 1)) * 256 + c * 16 + (hi & 1) * 8,
                       pk.b, 8);
    }
    psum += __shfl_xor(psum, 16);
    psum += __shfl_xor(psum, 32);
    lsum = lsum * scale + psum;
#pragma unroll
    for (int od = 0; od < 4; ++od)
#pragma unroll
      for (int r = 0; r < 4; ++r) o[od][r] *= scale;

    const char* vb = &VL[b3][0] + lane * 16;
#pragma unroll
    for (int od = 0; od < 4; ++od)
#pragma unroll
      for (int kk = 0; kk < 2; ++kk) {
        bf16x8 vf = *(const bf16x8*)(vb + od * 2048 + kk * 1024);
        bf16x8 pa = *(const bf16x8*)(plw + kk * 1024 + lane * 16);
        o[od] = mfma16(vf, pa, o[od]);
      }

    if (kt < 14) { VMCNT(2); } else if (kt == 14) { VMCNT0(); }
    if (kt < 15) { __builtin_amdgcn_sched_barrier(0); BAR(); __builtin_amdgcn_sched_barrier(0); }
  }

  // Epilogue -> Ogf granule layout. Lane owns q = c; O rows dk = od*16+hi*4+r.
  // Out-row m = b*1024 + q0 + c (rg = (b*1024+q0)>>4, row-in-group = c);
  // out-col k = h*64 + od*16 + hi*4 + r.
  float invl = 1.0f / lsum;
  int b_ = bh >> 4, h = bh & 15;
  int rg = ((b_ << 10) + q0) >> 4;
#pragma unroll
  for (int od = 0; od < 4; ++od) {
    union { bf16_t b[4]; } pk;
#pragma unroll
    for (int r = 0; r < 4; ++r) pk.b[r] = (bf16_t)(o[od][r] * invl);
    int kt2 = (h << 1) + (od >> 1);
    int lp = ((od & 1) * 2 + (hi >> 1)) * 16 + c;
    int el = (hi & 1) * 4;
    __builtin_memcpy(&Ogf[((size_t)(rg * 32 + kt2) * 64 + lp) * 8 + el], pk.b, 8);
  }
}

extern "C" void kernel_launch(void* const* d_in, const int* in_sizes, int n_in,
                              void* d_out, int out_size, void* d_ws, size_t ws_size,
                              hipStream_t stream) {
  const float* x = (const float*)d_in[0];
  const int* pos = (const int*)d_in[1];
  const float* Wq = (const float*)d_in[2];
  const float* bq = (const float*)d_in[3];
  const float* Wk = (const float*)d_in[4];
  const float* bk = (const float*)d_in[5];
  const float* Wv = (const float*)d_in[6];
  const float* bv = (const float*)d_in[7];
  const float* Wo = (const float*)d_in[8];
  const float* bo = (const float*)d_in[9];
  float* out = (float*)d_out;

  // ws: [0,16M) Xf (granule layout; reused as Ogf) | [16M,24M) Wf (granule,
  //     Wq|Wk|Wv|Wo = rg 0..255) | [24M,40M) Vt | [42M,..) rope table.
  // Q,K (bf16, 16MB each) live in d_out (32MB) -- dead before out-proj.
  char* ws = (char*)d_ws;
  bf16_t* Xf = (bf16_t*)ws;
  bf16_t* Wf = (bf16_t*)(ws + (16u << 20));
  bf16_t* Vt = (bf16_t*)(ws + (24u << 20));
  float2* rt = (float2*)(ws + (42u << 20));
  bf16_t* Qh = (bf16_t*)d_out;
  bf16_t* Kh = (bf16_t*)d_out + (size_t)8 * 1024 * 1024;
  bf16_t* Ogf = Xf;

  k_cast_xf<<<4096, 256, 0, stream>>>(x, Xf);
  k_cast_wf<<<2048, 256, 0, stream>>>(Wq, Wk, Wv, Wo, Wf);
  k_rope_table<<<128, 256, 0, stream>>>(pos, rt);

  k_gemm_qkv<<<1536, 256, 0, stream>>>(Xf, Wf, bq, bk, bv, rt, Qh, Kh, Vt);
  k_attn<<<1024, 512, 0, stream>>>(Qh, Kh, Vt, Ogf);
  k_gemm_out<<<512, 256, 0, stream>>>(Ogf, Wf, bo, out);
}

// Round 11
// 169.875 us; speedup vs baseline: 1.0972x; 1.0258x over previous
//
#include <hip/hip_runtime.h>
#include <hip/hip_bf16.h>

// Fused: QKV proj (+bias) -> RoPE(Q,K) -> MHA softmax -> out proj (+bias)
// B=8 S=1024 D=1024 H=16 Dk=64.
// GEMM engine (R11): zero-LDS direct-fragment (R10, first engine to beat the
// 23% pin) with (a) 512-thr 8-wave blocks (128x256 tile) for denser wave
// residency and (b) XCD-chunked swizzle (XCD owns 8 m-tiles x all n; A 2MB
// L2-resident, B streamed once) to cut L2-fill from 80MB toward ~50MB.

typedef __bf16 bf16_t;
typedef __bf16 bf16x8 __attribute__((ext_vector_type(8)));
typedef float  f32x4  __attribute__((ext_vector_type(4)));

static __device__ __forceinline__ f32x4 mfma16(bf16x8 a, bf16x8 b, f32x4 c) {
  return __builtin_amdgcn_mfma_f32_16x16x32_bf16(a, b, c, 0, 0, 0);
}
static __device__ __forceinline__ void gload_lds16(const void* g, void* l) {
  __builtin_amdgcn_global_load_lds((const __attribute__((address_space(1))) void*)g,
                                   (__attribute__((address_space(3))) void*)l,
                                   16, 0, 0);
}
#define VMCNT(n) asm volatile("s_waitcnt vmcnt(" #n ")" ::: "memory")
#define VMCNT0() asm volatile("s_waitcnt vmcnt(0)" ::: "memory")
#define BAR() __builtin_amdgcn_s_barrier()

#if __has_builtin(__builtin_amdgcn_exp2f)
#define EXP2F(x) __builtin_amdgcn_exp2f(x)
#else
#define EXP2F(x) exp2f(x)
#endif

// ---------------- prep: fragment-granule swizzle casts ----------------
// Granule (rg,kt,lane) at elem offset (rg*32+kt)*512 + lane*8 holds
// M[rg*16 + (lane&15)][kt*32 + (lane>>4)*8 .. +8) as bf16.
__global__ void k_cast_xf(const float* __restrict__ x, bf16_t* __restrict__ Xf) {
  int g = blockIdx.x * 256 + threadIdx.x;        // 1,048,576 granules (8192x1024)
  int rg = g >> 11, kt = (g >> 6) & 31, lane = g & 63;
  int m = rg * 16 + (lane & 15);
  int k = kt * 32 + (lane >> 4) * 8;
  const float* s = x + (size_t)m * 1024 + k;
  float4 v0 = *(const float4*)s;
  float4 v1 = *(const float4*)(s + 4);
  union { bf16_t b[8]; } pk;
  pk.b[0] = (bf16_t)v0.x; pk.b[1] = (bf16_t)v0.y; pk.b[2] = (bf16_t)v0.z; pk.b[3] = (bf16_t)v0.w;
  pk.b[4] = (bf16_t)v1.x; pk.b[5] = (bf16_t)v1.y; pk.b[6] = (bf16_t)v1.z; pk.b[7] = (bf16_t)v1.w;
  __builtin_memcpy(Xf + (size_t)g * 8, pk.b, 16);
}

// Wf rowgroups: [0,64) Wq | [64,128) Wk | [128,192) Wv | [192,256) Wo
__global__ void k_cast_wf(const float* __restrict__ Wq, const float* __restrict__ Wk,
                          const float* __restrict__ Wv, const float* __restrict__ Wo,
                          bf16_t* __restrict__ Wf) {
  int g = blockIdx.x * 256 + threadIdx.x;        // 524,288 granules (4096x1024)
  int rg = g >> 11, kt = (g >> 6) & 31, lane = g & 63;
  const float* src = (rg < 64) ? Wq : (rg < 128) ? Wk : (rg < 192) ? Wv : Wo;
  int row = (rg & 63) * 16 + (lane & 15);
  int k = kt * 32 + (lane >> 4) * 8;
  const float* s = src + (size_t)row * 1024 + k;
  float4 v0 = *(const float4*)s;
  float4 v1 = *(const float4*)(s + 4);
  union { bf16_t b[8]; } pk;
  pk.b[0] = (bf16_t)v0.x; pk.b[1] = (bf16_t)v0.y; pk.b[2] = (bf16_t)v0.z; pk.b[3] = (bf16_t)v0.w;
  pk.b[4] = (bf16_t)v1.x; pk.b[5] = (bf16_t)v1.y; pk.b[6] = (bf16_t)v1.z; pk.b[7] = (bf16_t)v1.w;
  __builtin_memcpy(Wf + (size_t)g * 8, pk.b, 16);
}

__global__ void k_rope_table(const int* __restrict__ pos, float2* __restrict__ rt) {
  int s = blockIdx.x * 8 + (threadIdx.x >> 5);
  int f = threadIdx.x & 31;
  float p = (float)pos[s];
  float inv = powf(10000.0f, -(float)(2 * f) / 64.0f);
  float a = p * inv;
  rt[s * 32 + f] = make_float2(cosf(a), sinf(a));
}

// ==== R11 direct-fragment GEMM body: 128x256 tile, 8 waves (2M x 4N) ====
// Per wave 64x64 (acc[4][4]); per iter (BK=32): 8 fragment loads, 16 MFMA.
// Double-buffered P/Q sets (statically named, rule #20).
#define GEMM_DIRECT_BODY(AfBase, BfBase)                                       \
  const int t = threadIdx.x;                                                   \
  const int lane = t & 63, w = t >> 6;                                         \
  const int hi = lane >> 4, c = lane & 15;                                     \
  const int wm = w >> 2, wn = w & 3;                                           \
  const bf16_t* Ab = (AfBase) + (size_t)((i0 >> 4) + wm * 4) * 16384 + lane * 8; \
  const bf16_t* Bb = (BfBase) + (size_t)((e0 >> 4) + wn * 4) * 16384 + lane * 8; \
  bf16x8 pa0, pa1, pa2, pa3, pb0, pb1, pb2, pb3;                               \
  bf16x8 qa0, qa1, qa2, qa3, qb0, qb1, qb2, qb3;                               \
  f32x4 acc[4][4] = {};                                                        \
  auto loadP = [&](int kt) {                                                   \
    pa0 = *(const bf16x8*)(Ab + kt * 512);                                     \
    pa1 = *(const bf16x8*)(Ab + 16384 + kt * 512);                             \
    pa2 = *(const bf16x8*)(Ab + 32768 + kt * 512);                             \
    pa3 = *(const bf16x8*)(Ab + 49152 + kt * 512);                             \
    pb0 = *(const bf16x8*)(Bb + kt * 512);                                     \
    pb1 = *(const bf16x8*)(Bb + 16384 + kt * 512);                             \
    pb2 = *(const bf16x8*)(Bb + 32768 + kt * 512);                             \
    pb3 = *(const bf16x8*)(Bb + 49152 + kt * 512);                             \
  };                                                                           \
  auto loadQ = [&](int kt) {                                                   \
    qa0 = *(const bf16x8*)(Ab + kt * 512);                                     \
    qa1 = *(const bf16x8*)(Ab + 16384 + kt * 512);                             \
    qa2 = *(const bf16x8*)(Ab + 32768 + kt * 512);                             \
    qa3 = *(const bf16x8*)(Ab + 49152 + kt * 512);                             \
    qb0 = *(const bf16x8*)(Bb + kt * 512);                                     \
    qb1 = *(const bf16x8*)(Bb + 16384 + kt * 512);                             \
    qb2 = *(const bf16x8*)(Bb + 32768 + kt * 512);                             \
    qb3 = *(const bf16x8*)(Bb + 49152 + kt * 512);                             \
  };                                                                           \
  auto compP = [&]() {                                                         \
    bf16x8 a_[4] = {pa0, pa1, pa2, pa3}, b_[4] = {pb0, pb1, pb2, pb3};         \
    _Pragma("unroll") for (int fr = 0; fr < 4; ++fr)                           \
      _Pragma("unroll") for (int nc = 0; nc < 4; ++nc)                         \
        acc[fr][nc] = mfma16(a_[fr], b_[nc], acc[fr][nc]);                     \
  };                                                                           \
  auto compQ = [&]() {                                                         \
    bf16x8 a_[4] = {qa0, qa1, qa2, qa3}, b_[4] = {qb0, qb1, qb2, qb3};         \
    _Pragma("unroll") for (int fr = 0; fr < 4; ++fr)                           \
      _Pragma("unroll") for (int nc = 0; nc < 4; ++nc)                         \
        acc[fr][nc] = mfma16(a_[fr], b_[nc], acc[fr][nc]);                     \
  };                                                                           \
  loadP(0);                                                                    \
  loadQ(1);                                                                    \
  _Pragma("unroll 3")                                                          \
  for (int jj = 0; jj < 15; ++jj) {                                            \
    compP(); loadP(jj * 2 + 2);                                                \
    compQ(); loadQ(jj * 2 + 3);                                                \
  }                                                                            \
  compP();                                                                     \
  compQ();

// ---------------- fused QKV GEMM: N=3072 (Wq|Wk|Wv concat) ----------------
// 768 blocks, 512 thr. XCD x owns m in [8x,8x+8) x all 12 n; within the XCD
// m is fastest so each B-tile (512KB) is used by 8 consecutive blocks then
// retired; A chunk (2MB) stays L2-resident.
__global__ __launch_bounds__(512) void k_gemm_qkv(
    const bf16_t* __restrict__ Xf, const bf16_t* __restrict__ Wf,
    const float* __restrict__ bq, const float* __restrict__ bk,
    const float* __restrict__ bv, const float2* __restrict__ rt,
    bf16_t* __restrict__ Qh, bf16_t* __restrict__ Kh, bf16_t* __restrict__ Vt) {
  const int bid = blockIdx.x;
  const int x = bid & 7, q = bid >> 3;           // q in [0,96)
  const int i0 = (x * 8 + (q & 7)) * 128;
  const int e0 = (q >> 3) * 256;

  GEMM_DIRECT_BODY(Xf, Wf)

  // Epilogue: one head per wave (64-col window at ez0).
  const int z = e0 >> 10;                       // 0:Q 1:K 2:V (4 n-tiles per z)
  const int ez0 = (e0 & 1023) + wn * 64;        // multiple of 64
  const int h = ez0 >> 6;
  const float* bias = (z == 0) ? bq : (z == 1) ? bk : bv;
  if (z == 2) {
#pragma unroll
    for (int fr = 0; fr < 4; ++fr) {
      int i = i0 + wm * 64 + fr * 16 + hi * 4;
      int b_ = i >> 10, s = i & 1023;
#pragma unroll
      for (int nc = 0; nc < 4; ++nc) {
        int dk = nc * 16 + c;
        float bv_ = bias[ez0 + dk];
        union { bf16_t b[4]; } pk;
#pragma unroll
        for (int r = 0; r < 4; ++r) pk.b[r] = (bf16_t)(acc[fr][nc][r] + bv_);
        __builtin_memcpy(&Vt[((size_t)((b_ * 16 + h) * 64 + dk)) * 1024 + s], pk.b, 8);
      }
    }
  } else {
    bf16_t* O = (z == 0) ? Qh : Kh;
    // Q folds 1/sqrt(64) * log2(e): attn softmax runs in exp2 domain.
    const float scl = (z == 0) ? 0.18033688011112042f : 1.0f;
#pragma unroll
    for (int fr = 0; fr < 4; ++fr) {
      int i = i0 + wm * 64 + fr * 16 + hi * 4;
      int b_ = i >> 10, sbase = i & 1023;
      size_t obase = (size_t)((b_ * 16 + h) * 1024);
#pragma unroll
      for (int nc = 0; nc < 2; ++nc) {          // f<32; partner f+32 = frag nc+2
        int f = nc * 16 + c;
        float b1_ = bias[ez0 + f], b2_ = bias[ez0 + f + 32];
#pragma unroll
        for (int r = 0; r < 4; ++r) {
          int s = sbase + r;
          float2 cs = rt[s * 32 + f];
          float q1 = acc[fr][nc][r] + b1_;
          float q2 = acc[fr][nc + 2][r] + b2_;
          O[(obase + s) * 64 + f] = (bf16_t)((q1 * cs.x - q2 * cs.y) * scl);
          O[(obase + s) * 64 + f + 32] = (bf16_t)((q1 * cs.y + q2 * cs.x) * scl);
        }
      }
    }
  }
}

// ---------------- out projection: 256 blocks = XCD-chunked 64m x 4n --------
__global__ __launch_bounds__(512) void k_gemm_out(
    const bf16_t* __restrict__ Ogf, const bf16_t* __restrict__ Wf,
    const float* __restrict__ bo, float* __restrict__ out) {
  const int bid = blockIdx.x;
  const int x = bid & 7, q = bid >> 3;           // q in [0,32)
  const int i0 = (x * 8 + (q & 7)) * 128;
  const int e0 = (q >> 3) * 256;
  const bf16_t* WfO = Wf + (size_t)192 * 16384;

  GEMM_DIRECT_BODY(Ogf, WfO)

#pragma unroll
  for (int fr = 0; fr < 4; ++fr) {
    int i = i0 + wm * 64 + fr * 16 + hi * 4;
#pragma unroll
    for (int nc = 0; nc < 4; ++nc) {
      int e = e0 + wn * 64 + nc * 16 + c;
      float bv_ = bo[e];
#pragma unroll
      for (int r = 0; r < 4; ++r)
        out[(size_t)(i + r) * 1024 + e] = acc[fr][nc][r] + bv_;
    }
  }
}

// ---------------- flash attention (R5 engine; epilogue -> granule Ogf) ------
__global__ __launch_bounds__(512) void k_attn(
    const bf16_t* __restrict__ Qh, const bf16_t* __restrict__ Kh,
    const bf16_t* __restrict__ Vt, bf16_t* __restrict__ Ogf) {
  __shared__ alignas(16) char KL[3][8192];
  __shared__ alignas(16) char VL[3][8192];
  __shared__ alignas(16) char PL[8][2048];
  const int t = threadIdx.x;
  const int lane = t & 63, w = t >> 6;
  const int hi = lane >> 4, c = lane & 15;
  const int bid = blockIdx.x;
  const int wg = (bid & 7) * 128 + (bid >> 3);
  const int bh = wg >> 3, qt = wg & 7;
  const size_t base = (size_t)bh * 64 * 1024;
  const int q0 = qt * 128 + w * 16;

  const int sc = t & 15, sks = (t >> 4) & 7, sfr = t >> 7;
  const bf16_t* srcK = Kh + base + (size_t)(sfr * 16 + sc) * 64 + sks * 8;
  const bf16_t* srcV = Vt + base + (size_t)(sfr * 16 + sc) * 1024 + sks * 8;
  auto stage = [&](int b3, int kt) {
    gload_lds16(srcK + (size_t)kt * 64 * 64, &KL[b3][0] + t * 16);
    gload_lds16(srcV + kt * 64, &VL[b3][0] + t * 16);
  };

  bf16x8 qf[2];
  qf[0] = *(const bf16x8*)&Qh[base + (size_t)(q0 + c) * 64 + hi * 8];
  qf[1] = *(const bf16x8*)&Qh[base + (size_t)(q0 + c) * 64 + 32 + hi * 8];

  f32x4 o[4] = {};
  float m = -1e30f, lsum = 0.f;

  stage(0, 0);
  stage(1, 1);
  VMCNT(2);
  BAR();

  char* const plw = &PL[w][0];
  for (int kt = 0; kt < 16; ++kt) {
    const int b3 = kt % 3;
    if (kt + 2 < 16) stage((kt + 2) % 3, kt + 2);

    const char* kb = &KL[b3][0] + lane * 16;
    f32x4 st[4] = {};
#pragma unroll
    for (int ni = 0; ni < 4; ++ni)
#pragma unroll
      for (int kk = 0; kk < 2; ++kk)
        st[ni] = mfma16(*(const bf16x8*)(kb + ni * 2048 + kk * 1024), qf[kk], st[ni]);

    float pmax = -1e30f;
#pragma unroll
    for (int ni = 0; ni < 4; ++ni)
#pragma unroll
      for (int r = 0; r < 4; ++r) pmax = fmaxf(pmax, st[ni][r]);
    pmax = fmaxf(pmax, __shfl_xor(pmax, 16));
    pmax = fmaxf(pmax, __shfl_xor(pmax, 32));
    float mn = fmaxf(m, pmax);
    float scale = EXP2F(m - mn);
    m = mn;
    float psum = 0.f;
#pragma unroll
    for (int ni = 0; ni < 4; ++ni) {
      union { bf16_t b[4]; } pk;
#pragma unroll
      for (int r = 0; r < 4; ++r) {
        float p = EXP2F(st[ni][r] - mn);
        psum += p;
        pk.b[r] = (bf16_t)p;
      }
      __builtin_memcpy(plw + (ni * 2 + (hi >> 1)) * 256 + c * 16 + (hi & 1) * 8,
                       pk.b, 8);
    }
    psum += __shfl_xor(psum, 16);
    psum += __shfl_xor(psum, 32);
    lsum = lsum * scale + psum;
#pragma unroll
    for (int od = 0; od < 4; ++od)
#pragma unroll
      for (int r = 0; r < 4; ++r) o[od][r] *= scale;

    const char* vb = &VL[b3][0] + lane * 16;
#pragma unroll
    for (int od = 0; od < 4; ++od)
#pragma unroll
      for (int kk = 0; kk < 2; ++kk) {
        bf16x8 vf = *(const bf16x8*)(vb + od * 2048 + kk * 1024);
        bf16x8 pa = *(const bf16x8*)(plw + kk * 1024 + lane * 16);
        o[od] = mfma16(vf, pa, o[od]);
      }

    if (kt < 14) { VMCNT(2); } else if (kt == 14) { VMCNT0(); }
    if (kt < 15) { __builtin_amdgcn_sched_barrier(0); BAR(); __builtin_amdgcn_sched_barrier(0); }
  }

  // Epilogue -> Ogf granule layout (rg = out-row group, col k = h*64 + dk).
  float invl = 1.0f / lsum;
  int b_ = bh >> 4, h = bh & 15;
  int rg = ((b_ << 10) + q0) >> 4;
#pragma unroll
  for (int od = 0; od < 4; ++od) {
    union { bf16_t b[4]; } pk;
#pragma unroll
    for (int r = 0; r < 4; ++r) pk.b[r] = (bf16_t)(o[od][r] * invl);
    int kt2 = (h << 1) + (od >> 1);
    int lp = ((od & 1) * 2 + (hi >> 1)) * 16 + c;
    int el = (hi & 1) * 4;
    __builtin_memcpy(&Ogf[((size_t)(rg * 32 + kt2) * 64 + lp) * 8 + el], pk.b, 8);
  }
}

extern "C" void kernel_launch(void* const* d_in, const int* in_sizes, int n_in,
                              void* d_out, int out_size, void* d_ws, size_t ws_size,
                              hipStream_t stream) {
  const float* x = (const float*)d_in[0];
  const int* pos = (const int*)d_in[1];
  const float* Wq = (const float*)d_in[2];
  const float* bq = (const float*)d_in[3];
  const float* Wk = (const float*)d_in[4];
  const float* bk = (const float*)d_in[5];
  const float* Wv = (const float*)d_in[6];
  const float* bv = (const float*)d_in[7];
  const float* Wo = (const float*)d_in[8];
  const float* bo = (const float*)d_in[9];
  float* out = (float*)d_out;

  // ws: [0,16M) Xf (granule; reused as Ogf) | [16M,24M) Wf (granule, Wq|Wk|Wv|Wo)
  //     [24M,40M) Vt | [42M,..) rope table.  Q,K live in d_out (32MB).
  char* ws = (char*)d_ws;
  bf16_t* Xf = (bf16_t*)ws;
  bf16_t* Wf = (bf16_t*)(ws + (16u << 20));
  bf16_t* Vt = (bf16_t*)(ws + (24u << 20));
  float2* rt = (float2*)(ws + (42u << 20));
  bf16_t* Qh = (bf16_t*)d_out;
  bf16_t* Kh = (bf16_t*)d_out + (size_t)8 * 1024 * 1024;
  bf16_t* Ogf = Xf;

  k_cast_xf<<<4096, 256, 0, stream>>>(x, Xf);
  k_cast_wf<<<2048, 256, 0, stream>>>(Wq, Wk, Wv, Wo, Wf);
  k_rope_table<<<128, 256, 0, stream>>>(pos, rt);

  k_gemm_qkv<<<768, 512, 0, stream>>>(Xf, Wf, bq, bk, bv, rt, Qh, Kh, Vt);
  k_attn<<<1024, 512, 0, stream>>>(Qh, Kh, Vt, Ogf);
  k_gemm_out<<<256, 512, 0, stream>>>(Ogf, Wf, bo, out);
}

// Round 12
// 164.294 us; speedup vs baseline: 1.1345x; 1.0340x over previous
//
#include <hip/hip_runtime.h>
#include <hip/hip_bf16.h>

// Fused: QKV proj (+bias) -> RoPE(Q,K) -> MHA softmax -> out proj (+bias)
// B=8 S=1024 D=1024 H=16 Dk=64.
// R12: GEMMs = R11 zero-LDS direct-fragment engine (unchanged). ATTENTION is
// rewritten barrier-free: K and V^T are emitted by the QKV epilogue in MFMA
// fragment-granule layout; attn reads fragments directly global->VGPR (L2-hot,
// XCD-local), each wave owns 32 q-rows (2 q-sets share every K/V read, halving
// L2 traffic), K double-buffered. Only wave-private P LDS remains (no sync).

typedef __bf16 bf16_t;
typedef __bf16 bf16x8 __attribute__((ext_vector_type(8)));
typedef float  f32x4  __attribute__((ext_vector_type(4)));

static __device__ __forceinline__ f32x4 mfma16(bf16x8 a, bf16x8 b, f32x4 c) {
  return __builtin_amdgcn_mfma_f32_16x16x32_bf16(a, b, c, 0, 0, 0);
}

#if __has_builtin(__builtin_amdgcn_exp2f)
#define EXP2F(x) __builtin_amdgcn_exp2f(x)
#else
#define EXP2F(x) exp2f(x)
#endif

// ---------------- prep: fragment-granule swizzle casts ----------------
// Granule (rg,kt,lane) at elem offset (rg*32+kt)*512 + lane*8 holds
// M[rg*16 + (lane&15)][kt*32 + (lane>>4)*8 .. +8) as bf16.
__global__ void k_cast_xf(const float* __restrict__ x, bf16_t* __restrict__ Xf) {
  int g = blockIdx.x * 256 + threadIdx.x;        // 1,048,576 granules (8192x1024)
  int rg = g >> 11, kt = (g >> 6) & 31, lane = g & 63;
  int m = rg * 16 + (lane & 15);
  int k = kt * 32 + (lane >> 4) * 8;
  const float* s = x + (size_t)m * 1024 + k;
  float4 v0 = *(const float4*)s;
  float4 v1 = *(const float4*)(s + 4);
  union { bf16_t b[8]; } pk;
  pk.b[0] = (bf16_t)v0.x; pk.b[1] = (bf16_t)v0.y; pk.b[2] = (bf16_t)v0.z; pk.b[3] = (bf16_t)v0.w;
  pk.b[4] = (bf16_t)v1.x; pk.b[5] = (bf16_t)v1.y; pk.b[6] = (bf16_t)v1.z; pk.b[7] = (bf16_t)v1.w;
  __builtin_memcpy(Xf + (size_t)g * 8, pk.b, 16);
}

// Wf rowgroups: [0,64) Wq | [64,128) Wk | [128,192) Wv | [192,256) Wo
__global__ void k_cast_wf(const float* __restrict__ Wq, const float* __restrict__ Wk,
                          const float* __restrict__ Wv, const float* __restrict__ Wo,
                          bf16_t* __restrict__ Wf) {
  int g = blockIdx.x * 256 + threadIdx.x;        // 524,288 granules (4096x1024)
  int rg = g >> 11, kt = (g >> 6) & 31, lane = g & 63;
  const float* src = (rg < 64) ? Wq : (rg < 128) ? Wk : (rg < 192) ? Wv : Wo;
  int row = (rg & 63) * 16 + (lane & 15);
  int k = kt * 32 + (lane >> 4) * 8;
  const float* s = src + (size_t)row * 1024 + k;
  float4 v0 = *(const float4*)s;
  float4 v1 = *(const float4*)(s + 4);
  union { bf16_t b[8]; } pk;
  pk.b[0] = (bf16_t)v0.x; pk.b[1] = (bf16_t)v0.y; pk.b[2] = (bf16_t)v0.z; pk.b[3] = (bf16_t)v0.w;
  pk.b[4] = (bf16_t)v1.x; pk.b[5] = (bf16_t)v1.y; pk.b[6] = (bf16_t)v1.z; pk.b[7] = (bf16_t)v1.w;
  __builtin_memcpy(Wf + (size_t)g * 8, pk.b, 16);
}

__global__ void k_rope_table(const int* __restrict__ pos, float2* __restrict__ rt) {
  int s = blockIdx.x * 8 + (threadIdx.x >> 5);
  int f = threadIdx.x & 31;
  float p = (float)pos[s];
  float inv = powf(10000.0f, -(float)(2 * f) / 64.0f);
  float a = p * inv;
  rt[s * 32 + f] = make_float2(cosf(a), sinf(a));
}

// ==== direct-fragment GEMM body: 128x256 tile, 8 waves (2M x 4N) [R11] ====
#define GEMM_DIRECT_BODY(AfBase, BfBase)                                       \
  const int t = threadIdx.x;                                                   \
  const int lane = t & 63, w = t >> 6;                                         \
  const int hi = lane >> 4, c = lane & 15;                                     \
  const int wm = w >> 2, wn = w & 3;                                           \
  const bf16_t* Ab = (AfBase) + (size_t)((i0 >> 4) + wm * 4) * 16384 + lane * 8; \
  const bf16_t* Bb = (BfBase) + (size_t)((e0 >> 4) + wn * 4) * 16384 + lane * 8; \
  bf16x8 pa0, pa1, pa2, pa3, pb0, pb1, pb2, pb3;                               \
  bf16x8 qa0, qa1, qa2, qa3, qb0, qb1, qb2, qb3;                               \
  f32x4 acc[4][4] = {};                                                        \
  auto loadP = [&](int kt) {                                                   \
    pa0 = *(const bf16x8*)(Ab + kt * 512);                                     \
    pa1 = *(const bf16x8*)(Ab + 16384 + kt * 512);                             \
    pa2 = *(const bf16x8*)(Ab + 32768 + kt * 512);                             \
    pa3 = *(const bf16x8*)(Ab + 49152 + kt * 512);                             \
    pb0 = *(const bf16x8*)(Bb + kt * 512);                                     \
    pb1 = *(const bf16x8*)(Bb + 16384 + kt * 512);                             \
    pb2 = *(const bf16x8*)(Bb + 32768 + kt * 512);                             \
    pb3 = *(const bf16x8*)(Bb + 49152 + kt * 512);                             \
  };                                                                           \
  auto loadQ = [&](int kt) {                                                   \
    qa0 = *(const bf16x8*)(Ab + kt * 512);                                     \
    qa1 = *(const bf16x8*)(Ab + 16384 + kt * 512);                             \
    qa2 = *(const bf16x8*)(Ab + 32768 + kt * 512);                             \
    qa3 = *(const bf16x8*)(Ab + 49152 + kt * 512);                             \
    qb0 = *(const bf16x8*)(Bb + kt * 512);                                     \
    qb1 = *(const bf16x8*)(Bb + 16384 + kt * 512);                             \
    qb2 = *(const bf16x8*)(Bb + 32768 + kt * 512);                             \
    qb3 = *(const bf16x8*)(Bb + 49152 + kt * 512);                             \
  };                                                                           \
  auto compP = [&]() {                                                         \
    bf16x8 a_[4] = {pa0, pa1, pa2, pa3}, b_[4] = {pb0, pb1, pb2, pb3};         \
    _Pragma("unroll") for (int fr = 0; fr < 4; ++fr)                           \
      _Pragma("unroll") for (int nc = 0; nc < 4; ++nc)                         \
        acc[fr][nc] = mfma16(a_[fr], b_[nc], acc[fr][nc]);                     \
  };                                                                           \
  auto compQ = [&]() {                                                         \
    bf16x8 a_[4] = {qa0, qa1, qa2, qa3}, b_[4] = {qb0, qb1, qb2, qb3};         \
    _Pragma("unroll") for (int fr = 0; fr < 4; ++fr)                           \
      _Pragma("unroll") for (int nc = 0; nc < 4; ++nc)                         \
        acc[fr][nc] = mfma16(a_[fr], b_[nc], acc[fr][nc]);                     \
  };                                                                           \
  loadP(0);                                                                    \
  loadQ(1);                                                                    \
  _Pragma("unroll 3")                                                          \
  for (int jj = 0; jj < 15; ++jj) {                                            \
    compP(); loadP(jj * 2 + 2);                                                \
    compQ(); loadQ(jj * 2 + 3);                                                \
  }                                                                            \
  compP();                                                                     \
  compQ();

// ---------------- fused QKV GEMM: N=3072 (Wq|Wk|Wv concat) ----------------
// 768 blocks, 512 thr, XCD-chunked (R11). Epilogues: Q row-major (+rope,
// exp2-scale), K -> fragment-granule (+rope), V -> V^T fragment-granule.
__global__ __launch_bounds__(512) void k_gemm_qkv(
    const bf16_t* __restrict__ Xf, const bf16_t* __restrict__ Wf,
    const float* __restrict__ bq, const float* __restrict__ bk,
    const float* __restrict__ bv, const float2* __restrict__ rt,
    bf16_t* __restrict__ Qh, bf16_t* __restrict__ Kg, bf16_t* __restrict__ Vg) {
  const int bid = blockIdx.x;
  const int x = bid & 7, q = bid >> 3;           // q in [0,96)
  const int i0 = (x * 8 + (q & 7)) * 128;
  const int e0 = (q >> 3) * 256;

  GEMM_DIRECT_BODY(Xf, Wf)

  const int z = e0 >> 10;                       // 0:Q 1:K 2:V
  const int ez0 = (e0 & 1023) + wn * 64;        // multiple of 64
  const int h = ez0 >> 6;
  const float* bias = (z == 0) ? bq : (z == 1) ? bk : bv;
  if (z == 2) {
    // V -> V^T granule: granule g=(bh*4 + dkgrp)*32 + (s>>5); lane=(dk&15)|
    // (((s>>3)&3)<<4); elem=s&7. Thread's 4 consecutive s -> one 8B write.
#pragma unroll
    for (int fr = 0; fr < 4; ++fr) {
      int i = i0 + wm * 64 + fr * 16 + hi * 4;
      int b_ = i >> 10, sbase = i & 1023;
      int bhv = b_ * 16 + h;
      int lane_ = c | (((sbase >> 3) & 3) << 4);
#pragma unroll
      for (int nc = 0; nc < 4; ++nc) {
        float bv_ = bias[ez0 + nc * 16 + c];
        union { bf16_t b[4]; } pk;
#pragma unroll
        for (int r = 0; r < 4; ++r) pk.b[r] = (bf16_t)(acc[fr][nc][r] + bv_);
        size_t g = (size_t)(bhv * 4 + nc) * 32 + (sbase >> 5);
        __builtin_memcpy(&Vg[g * 512 + lane_ * 8 + (sbase & 7)], pk.b, 8);
      }
    }
  } else if (z == 0) {
    // Q row-major with rope; folds 1/sqrt(64)*log2(e) (exp2-domain softmax).
    const float scl = 0.18033688011112042f;
#pragma unroll
    for (int fr = 0; fr < 4; ++fr) {
      int i = i0 + wm * 64 + fr * 16 + hi * 4;
      int b_ = i >> 10, sbase = i & 1023;
      size_t obase = (size_t)((b_ * 16 + h) * 1024);
#pragma unroll
      for (int nc = 0; nc < 2; ++nc) {          // f<32; partner f+32 = frag nc+2
        int f = nc * 16 + c;
        float b1_ = bias[ez0 + f], b2_ = bias[ez0 + f + 32];
#pragma unroll
        for (int r = 0; r < 4; ++r) {
          int s = sbase + r;
          float2 cs = rt[s * 32 + f];
          float q1 = acc[fr][nc][r] + b1_;
          float q2 = acc[fr][nc + 2][r] + b2_;
          Qh[(obase + s) * 64 + f] = (bf16_t)((q1 * cs.x - q2 * cs.y) * scl);
          Qh[(obase + s) * 64 + f + 32] = (bf16_t)((q1 * cs.y + q2 * cs.x) * scl);
        }
      }
    }
  } else {
    // K -> granule with rope: granule g=(bh*64 + (s>>4))*2 + (dk>>5);
    // lane=(s&15)|(((dk>>3)&3)<<4); elem=dk&7. dk and dk+32 share lane/elem,
    // differ by one granule (+512 elems).
#pragma unroll
    for (int fr = 0; fr < 4; ++fr) {
      int i = i0 + wm * 64 + fr * 16 + hi * 4;
      int b_ = i >> 10, sbase = i & 1023;
      bf16_t* gb = Kg + (size_t)((b_ * 16 + h) * 64 + (sbase >> 4)) * 1024;
#pragma unroll
      for (int nc = 0; nc < 2; ++nc) {
        int f = nc * 16 + c;
        float b1_ = bias[ez0 + f], b2_ = bias[ez0 + f + 32];
        int laneHi = (nc * 2 + (c >> 3)) << 4;
#pragma unroll
        for (int r = 0; r < 4; ++r) {
          int s = sbase + r;
          float2 cs = rt[s * 32 + f];
          float q1 = acc[fr][nc][r] + b1_;
          float q2 = acc[fr][nc + 2][r] + b2_;
          size_t off = (size_t)((hi * 4 + r) | laneHi) * 8 + (c & 7);
          gb[off] = (bf16_t)(q1 * cs.x - q2 * cs.y);
          gb[off + 512] = (bf16_t)(q1 * cs.y + q2 * cs.x);
        }
      }
    }
  }
}

// ---------------- out projection: 256 blocks, XCD-chunked [R11] -----------
__global__ __launch_bounds__(512) void k_gemm_out(
    const bf16_t* __restrict__ Ogf, const bf16_t* __restrict__ Wf,
    const float* __restrict__ bo, float* __restrict__ out) {
  const int bid = blockIdx.x;
  const int x = bid & 7, q = bid >> 3;           // q in [0,32)
  const int i0 = (x * 8 + (q & 7)) * 128;
  const int e0 = (q >> 3) * 256;
  const bf16_t* WfO = Wf + (size_t)192 * 16384;

  GEMM_DIRECT_BODY(Ogf, WfO)

#pragma unroll
  for (int fr = 0; fr < 4; ++fr) {
    int i = i0 + wm * 64 + fr * 16 + hi * 4;
#pragma unroll
    for (int nc = 0; nc < 4; ++nc) {
      int e = e0 + wn * 64 + nc * 16 + c;
      float bv_ = bo[e];
#pragma unroll
      for (int r = 0; r < 4; ++r)
        out[(size_t)(i + r) * 1024 + e] = acc[fr][nc][r] + bv_;
    }
  }
}

// ---------------- flash attention (R12: barrier-free direct-fragment) ------
// 512 blocks x 512 thr. XCD x owns bh in [16x,16x+16) (K+V granules 4MB = L2).
// Wave = 32 q-rows (2 q-sets A/B share every K/V fragment read -> L2 traffic
// halved). K double-buffered (kp/kq); V loaded at iter top, used at bottom.
// NO barriers, NO staging LDS; PL is wave-private (lgkm-ordered only).
__global__ __launch_bounds__(512) void k_attn(
    const bf16_t* __restrict__ Qh, const bf16_t* __restrict__ Kg,
    const bf16_t* __restrict__ Vg, bf16_t* __restrict__ Ogf) {
  __shared__ alignas(16) char PL[8][2048];
  const int t = threadIdx.x;
  const int lane = t & 63, w = t >> 6;
  const int hi = lane >> 4, c = lane & 15;
  const int bid = blockIdx.x;
  const int wg = (bid & 7) * 64 + (bid >> 3);
  const int bh = wg >> 2, qt = wg & 3;
  const int q0 = qt * 256 + w * 32;
  const size_t qbase = (size_t)bh * 64 * 1024;

  const bf16_t* Kb = Kg + (size_t)bh * 65536 + lane * 8;
  const bf16_t* Vb = Vg + (size_t)bh * 65536 + lane * 8;

  bf16x8 qfA[2], qfB[2];
#pragma unroll
  for (int kk = 0; kk < 2; ++kk) {
    qfA[kk] = *(const bf16x8*)&Qh[qbase + (size_t)(q0 + c) * 64 + kk * 32 + hi * 8];
    qfB[kk] = *(const bf16x8*)&Qh[qbase + (size_t)(q0 + 16 + c) * 64 + kk * 32 + hi * 8];
  }

  f32x4 oA[4] = {}, oB[4] = {};
  float mA = -1e30f, lA = 0.f, mB = -1e30f, lB = 0.f;
  char* const plw = &PL[w][0];

  bf16x8 kp[8], kq[8], vv[8];
#pragma unroll
  for (int ni = 0; ni < 4; ++ni)
#pragma unroll
    for (int kk = 0; kk < 2; ++kk)
      kp[ni * 2 + kk] = *(const bf16x8*)(Kb + (ni * 2 + kk) * 512);

#define SM_PV(ST, M, L, O)                                                     \
  {                                                                            \
    float pmax = -1e30f;                                                       \
    _Pragma("unroll") for (int ni = 0; ni < 4; ++ni)                           \
      _Pragma("unroll") for (int r = 0; r < 4; ++r)                            \
        pmax = fmaxf(pmax, ST[ni][r]);                                         \
    pmax = fmaxf(pmax, __shfl_xor(pmax, 16));                                  \
    pmax = fmaxf(pmax, __shfl_xor(pmax, 32));                                  \
    float mn = fmaxf(M, pmax);                                                 \
    float scale = EXP2F(M - mn);                                               \
    M = mn;                                                                    \
    float psum = 0.f;                                                          \
    _Pragma("unroll") for (int ni = 0; ni < 4; ++ni) {                         \
      union { bf16_t b[4]; } pk;                                               \
      _Pragma("unroll") for (int r = 0; r < 4; ++r) {                          \
        float p = EXP2F(ST[ni][r] - mn);                                       \
        psum += p;                                                             \
        pk.b[r] = (bf16_t)p;                                                   \
      }                                                                        \
      __builtin_memcpy(plw + (ni * 2 + (hi >> 1)) * 256 + c * 16 + (hi & 1) * 8, \
                       pk.b, 8);                                               \
    }                                                                          \
    psum += __shfl_xor(psum, 16);                                              \
    psum += __shfl_xor(psum, 32);                                              \
    L = L * scale + psum;                                                      \
    _Pragma("unroll") for (int od = 0; od < 4; ++od)                           \
      _Pragma("unroll") for (int r = 0; r < 4; ++r) O[od][r] *= scale;         \
    bf16x8 pa[2];                                                              \
    __builtin_memcpy(&pa[0], plw + lane * 16, 16);                             \
    __builtin_memcpy(&pa[1], plw + 1024 + lane * 16, 16);                      \
    _Pragma("unroll") for (int od = 0; od < 4; ++od)                           \
      _Pragma("unroll") for (int kk = 0; kk < 2; ++kk)                         \
        O[od] = mfma16(vv[od * 2 + kk], pa[kk], O[od]);                        \
  }

#define ATTN_TILE(KS, KN, KT)                                                  \
  {                                                                            \
    _Pragma("unroll") for (int od = 0; od < 4; ++od)                           \
      _Pragma("unroll") for (int kk = 0; kk < 2; ++kk)                         \
        vv[od * 2 + kk] = *(const bf16x8*)(Vb + (od * 32 + (KT) * 2 + kk) * 512); \
    f32x4 stA[4] = {}, stB[4] = {};                                            \
    _Pragma("unroll") for (int ni = 0; ni < 4; ++ni)                           \
      _Pragma("unroll") for (int kk = 0; kk < 2; ++kk)                         \
        stA[ni] = mfma16(KS[ni * 2 + kk], qfA[kk], stA[ni]);                   \
    _Pragma("unroll") for (int ni = 0; ni < 4; ++ni)                           \
      _Pragma("unroll") for (int kk = 0; kk < 2; ++kk)                         \
        stB[ni] = mfma16(KS[ni * 2 + kk], qfB[kk], stB[ni]);                   \
    if ((KT) + 1 < 16) {                                                       \
      _Pragma("unroll") for (int ni = 0; ni < 4; ++ni)                         \
        _Pragma("unroll") for (int kk = 0; kk < 2; ++kk)                       \
          KN[ni * 2 + kk] =                                                    \
              *(const bf16x8*)(Kb + (((KT) + 1) * 8 + ni * 2 + kk) * 512);     \
    }                                                                          \
    SM_PV(stA, mA, lA, oA)                                                     \
    SM_PV(stB, mB, lB, oB)                                                     \
  }

  for (int jj = 0; jj < 8; ++jj) {
    ATTN_TILE(kp, kq, jj * 2);
    ATTN_TILE(kq, kp, jj * 2 + 1);
  }
#undef ATTN_TILE
#undef SM_PV

  // Epilogue -> Ogf granule layout (both q-sets).
  int b_ = bh >> 4, h = bh & 15;
  float ivA = 1.f / lA, ivB = 1.f / lB;
  int rgA = ((b_ << 10) + q0) >> 4;
#pragma unroll
  for (int od = 0; od < 4; ++od) {
    union { bf16_t b[4]; } pk;
#pragma unroll
    for (int r = 0; r < 4; ++r) pk.b[r] = (bf16_t)(oA[od][r] * ivA);
    int kt2 = (h << 1) + (od >> 1);
    int lp = ((od & 1) * 2 + (hi >> 1)) * 16 + c;
    int el = (hi & 1) * 4;
    __builtin_memcpy(&Ogf[((size_t)(rgA * 32 + kt2) * 64 + lp) * 8 + el], pk.b, 8);
  }
  int rgB = rgA + 1;
#pragma unroll
  for (int od = 0; od < 4; ++od) {
    union { bf16_t b[4]; } pk;
#pragma unroll
    for (int r = 0; r < 4; ++r) pk.b[r] = (bf16_t)(oB[od][r] * ivB);
    int kt2 = (h << 1) + (od >> 1);
    int lp = ((od & 1) * 2 + (hi >> 1)) * 16 + c;
    int el = (hi & 1) * 4;
    __builtin_memcpy(&Ogf[((size_t)(rgB * 32 + kt2) * 64 + lp) * 8 + el], pk.b, 8);
  }
}

extern "C" void kernel_launch(void* const* d_in, const int* in_sizes, int n_in,
                              void* d_out, int out_size, void* d_ws, size_t ws_size,
                              hipStream_t stream) {
  const float* x = (const float*)d_in[0];
  const int* pos = (const int*)d_in[1];
  const float* Wq = (const float*)d_in[2];
  const float* bq = (const float*)d_in[3];
  const float* Wk = (const float*)d_in[4];
  const float* bk = (const float*)d_in[5];
  const float* Wv = (const float*)d_in[6];
  const float* bv = (const float*)d_in[7];
  const float* Wo = (const float*)d_in[8];
  const float* bo = (const float*)d_in[9];
  float* out = (float*)d_out;

  // ws: [0,16M) Xf (granule; reused as Ogf) | [16M,24M) Wf (granule)
  //     [24M,40M) Vg (V^T granule) | [42M,..) rope table.
  // Qh (row-major) + Kg (granule) live in d_out (16MB each).
  char* ws = (char*)d_ws;
  bf16_t* Xf = (bf16_t*)ws;
  bf16_t* Wf = (bf16_t*)(ws + (16u << 20));
  bf16_t* Vg = (bf16_t*)(ws + (24u << 20));
  float2* rt = (float2*)(ws + (42u << 20));
  bf16_t* Qh = (bf16_t*)d_out;
  bf16_t* Kg = (bf16_t*)d_out + (size_t)8 * 1024 * 1024;
  bf16_t* Ogf = Xf;

  k_cast_xf<<<4096, 256, 0, stream>>>(x, Xf);
  k_cast_wf<<<2048, 256, 0, stream>>>(Wq, Wk, Wv, Wo, Wf);
  k_rope_table<<<128, 256, 0, stream>>>(pos, rt);

  k_gemm_qkv<<<768, 512, 0, stream>>>(Xf, Wf, bq, bk, bv, rt, Qh, Kg, Vg);
  k_attn<<<512, 512, 0, stream>>>(Qh, Kg, Vg, Ogf);
  k_gemm_out<<<256, 512, 0, stream>>>(Ogf, Wf, bo, out);
}

// Round 13
// 152.916 us; speedup vs baseline: 1.2189x; 1.0744x over previous
//
#include <hip/hip_runtime.h>
#include <hip/hip_bf16.h>

// Fused: QKV proj (+bias) -> RoPE(Q,K) -> MHA softmax -> out proj (+bias)
// B=8 S=1024 D=1024 H=16 Dk=64.
// R13: GEMMs = R11/R12 zero-LDS direct-fragment engine (+ setprio on MFMA
// clusters, T5: desynced waves). Attn = R12 barrier-free engine with FOUR
// q-sets per wave (64 q-rows): K/V fragment reads amortized 4x -> L2 traffic
// halved; sets processed sequentially (st live-range 16 VGPR). Prep fused
// into one kernel (cast_xf + cast_wf + rope).

typedef __bf16 bf16_t;
typedef __bf16 bf16x8 __attribute__((ext_vector_type(8)));
typedef float  f32x4  __attribute__((ext_vector_type(4)));

static __device__ __forceinline__ f32x4 mfma16(bf16x8 a, bf16x8 b, f32x4 c) {
  return __builtin_amdgcn_mfma_f32_16x16x32_bf16(a, b, c, 0, 0, 0);
}

#if __has_builtin(__builtin_amdgcn_exp2f)
#define EXP2F(x) __builtin_amdgcn_exp2f(x)
#else
#define EXP2F(x) exp2f(x)
#endif

// ---------------- prep (single kernel): granule casts + rope table --------
// Granule (rg,kt,lane) at elem offset (rg*32+kt)*512 + lane*8 holds
// M[rg*16 + (lane&15)][kt*32 + (lane>>4)*8 .. +8) as bf16.
__global__ void k_prep(const float* __restrict__ x, const float* __restrict__ Wq,
                       const float* __restrict__ Wk, const float* __restrict__ Wv,
                       const float* __restrict__ Wo, const int* __restrict__ pos,
                       bf16_t* __restrict__ Xf, bf16_t* __restrict__ Wf,
                       float2* __restrict__ rt) {
  const int bid = blockIdx.x;
  const int t = threadIdx.x;
  if (bid < 4096) {                     // x -> Xf granules (8192x1024)
    int g = bid * 256 + t;
    int rg = g >> 11, kt = (g >> 6) & 31, lane = g & 63;
    int m = rg * 16 + (lane & 15);
    int k = kt * 32 + (lane >> 4) * 8;
    const float* s = x + (size_t)m * 1024 + k;
    float4 v0 = *(const float4*)s;
    float4 v1 = *(const float4*)(s + 4);
    union { bf16_t b[8]; } pk;
    pk.b[0] = (bf16_t)v0.x; pk.b[1] = (bf16_t)v0.y; pk.b[2] = (bf16_t)v0.z; pk.b[3] = (bf16_t)v0.w;
    pk.b[4] = (bf16_t)v1.x; pk.b[5] = (bf16_t)v1.y; pk.b[6] = (bf16_t)v1.z; pk.b[7] = (bf16_t)v1.w;
    __builtin_memcpy(Xf + (size_t)g * 8, pk.b, 16);
  } else if (bid < 6144) {              // W -> Wf granules (rg: Wq|Wk|Wv|Wo)
    int g = (bid - 4096) * 256 + t;
    int rg = g >> 11, kt = (g >> 6) & 31, lane = g & 63;
    const float* src = (rg < 64) ? Wq : (rg < 128) ? Wk : (rg < 192) ? Wv : Wo;
    int row = (rg & 63) * 16 + (lane & 15);
    int k = kt * 32 + (lane >> 4) * 8;
    const float* s = src + (size_t)row * 1024 + k;
    float4 v0 = *(const float4*)s;
    float4 v1 = *(const float4*)(s + 4);
    union { bf16_t b[8]; } pk;
    pk.b[0] = (bf16_t)v0.x; pk.b[1] = (bf16_t)v0.y; pk.b[2] = (bf16_t)v0.z; pk.b[3] = (bf16_t)v0.w;
    pk.b[4] = (bf16_t)v1.x; pk.b[5] = (bf16_t)v1.y; pk.b[6] = (bf16_t)v1.z; pk.b[7] = (bf16_t)v1.w;
    __builtin_memcpy(Wf + (size_t)g * 8, pk.b, 16);
  } else {                              // rope table
    int rb = bid - 6144;                // [0,128)
    int s = rb * 8 + (t >> 5);
    int f = t & 31;
    float p = (float)pos[s];
    float inv = powf(10000.0f, -(float)(2 * f) / 64.0f);
    float a = p * inv;
    rt[s * 32 + f] = make_float2(cosf(a), sinf(a));
  }
}

// ==== direct-fragment GEMM body: 128x256 tile, 8 waves (2M x 4N) [R11] ====
#define GEMM_DIRECT_BODY(AfBase, BfBase)                                       \
  const int t = threadIdx.x;                                                   \
  const int lane = t & 63, w = t >> 6;                                         \
  const int hi = lane >> 4, c = lane & 15;                                     \
  const int wm = w >> 2, wn = w & 3;                                           \
  const bf16_t* Ab = (AfBase) + (size_t)((i0 >> 4) + wm * 4) * 16384 + lane * 8; \
  const bf16_t* Bb = (BfBase) + (size_t)((e0 >> 4) + wn * 4) * 16384 + lane * 8; \
  bf16x8 pa0, pa1, pa2, pa3, pb0, pb1, pb2, pb3;                               \
  bf16x8 qa0, qa1, qa2, qa3, qb0, qb1, qb2, qb3;                               \
  f32x4 acc[4][4] = {};                                                        \
  auto loadP = [&](int kt) {                                                   \
    pa0 = *(const bf16x8*)(Ab + kt * 512);                                     \
    pa1 = *(const bf16x8*)(Ab + 16384 + kt * 512);                             \
    pa2 = *(const bf16x8*)(Ab + 32768 + kt * 512);                             \
    pa3 = *(const bf16x8*)(Ab + 49152 + kt * 512);                             \
    pb0 = *(const bf16x8*)(Bb + kt * 512);                                     \
    pb1 = *(const bf16x8*)(Bb + 16384 + kt * 512);                             \
    pb2 = *(const bf16x8*)(Bb + 32768 + kt * 512);                             \
    pb3 = *(const bf16x8*)(Bb + 49152 + kt * 512);                             \
  };                                                                           \
  auto loadQ = [&](int kt) {                                                   \
    qa0 = *(const bf16x8*)(Ab + kt * 512);                                     \
    qa1 = *(const bf16x8*)(Ab + 16384 + kt * 512);                             \
    qa2 = *(const bf16x8*)(Ab + 32768 + kt * 512);                             \
    qa3 = *(const bf16x8*)(Ab + 49152 + kt * 512);                             \
    qb0 = *(const bf16x8*)(Bb + kt * 512);                                     \
    qb1 = *(const bf16x8*)(Bb + 16384 + kt * 512);                             \
    qb2 = *(const bf16x8*)(Bb + 32768 + kt * 512);                             \
    qb3 = *(const bf16x8*)(Bb + 49152 + kt * 512);                             \
  };                                                                           \
  auto compP = [&]() {                                                         \
    bf16x8 a_[4] = {pa0, pa1, pa2, pa3}, b_[4] = {pb0, pb1, pb2, pb3};         \
    __builtin_amdgcn_s_setprio(1);                                             \
    _Pragma("unroll") for (int fr = 0; fr < 4; ++fr)                           \
      _Pragma("unroll") for (int nc = 0; nc < 4; ++nc)                         \
        acc[fr][nc] = mfma16(a_[fr], b_[nc], acc[fr][nc]);                     \
    __builtin_amdgcn_s_setprio(0);                                             \
  };                                                                           \
  auto compQ = [&]() {                                                         \
    bf16x8 a_[4] = {qa0, qa1, qa2, qa3}, b_[4] = {qb0, qb1, qb2, qb3};         \
    __builtin_amdgcn_s_setprio(1);                                             \
    _Pragma("unroll") for (int fr = 0; fr < 4; ++fr)                           \
      _Pragma("unroll") for (int nc = 0; nc < 4; ++nc)                         \
        acc[fr][nc] = mfma16(a_[fr], b_[nc], acc[fr][nc]);                     \
    __builtin_amdgcn_s_setprio(0);                                             \
  };                                                                           \
  loadP(0);                                                                    \
  loadQ(1);                                                                    \
  _Pragma("unroll 3")                                                          \
  for (int jj = 0; jj < 15; ++jj) {                                            \
    compP(); loadP(jj * 2 + 2);                                                \
    compQ(); loadQ(jj * 2 + 3);                                                \
  }                                                                            \
  compP();                                                                     \
  compQ();

// ---------------- fused QKV GEMM: N=3072, 768 blocks, XCD-chunked ---------
__global__ __launch_bounds__(512) void k_gemm_qkv(
    const bf16_t* __restrict__ Xf, const bf16_t* __restrict__ Wf,
    const float* __restrict__ bq, const float* __restrict__ bk,
    const float* __restrict__ bv, const float2* __restrict__ rt,
    bf16_t* __restrict__ Qh, bf16_t* __restrict__ Kg, bf16_t* __restrict__ Vg) {
  const int bid = blockIdx.x;
  const int x = bid & 7, q = bid >> 3;           // q in [0,96)
  const int i0 = (x * 8 + (q & 7)) * 128;
  const int e0 = (q >> 3) * 256;

  GEMM_DIRECT_BODY(Xf, Wf)

  const int z = e0 >> 10;                       // 0:Q 1:K 2:V
  const int ez0 = (e0 & 1023) + wn * 64;        // multiple of 64
  const int h = ez0 >> 6;
  const float* bias = (z == 0) ? bq : (z == 1) ? bk : bv;
  if (z == 2) {
    // V -> V^T granule (see R12 ledger).
#pragma unroll
    for (int fr = 0; fr < 4; ++fr) {
      int i = i0 + wm * 64 + fr * 16 + hi * 4;
      int b_ = i >> 10, sbase = i & 1023;
      int bhv = b_ * 16 + h;
      int lane_ = c | (((sbase >> 3) & 3) << 4);
#pragma unroll
      for (int nc = 0; nc < 4; ++nc) {
        float bv_ = bias[ez0 + nc * 16 + c];
        union { bf16_t b[4]; } pk;
#pragma unroll
        for (int r = 0; r < 4; ++r) pk.b[r] = (bf16_t)(acc[fr][nc][r] + bv_);
        size_t g = (size_t)(bhv * 4 + nc) * 32 + (sbase >> 5);
        __builtin_memcpy(&Vg[g * 512 + lane_ * 8 + (sbase & 7)], pk.b, 8);
      }
    }
  } else if (z == 0) {
    // Q row-major with rope; folds 1/sqrt(64)*log2(e) (exp2-domain softmax).
    const float scl = 0.18033688011112042f;
#pragma unroll
    for (int fr = 0; fr < 4; ++fr) {
      int i = i0 + wm * 64 + fr * 16 + hi * 4;
      int b_ = i >> 10, sbase = i & 1023;
      size_t obase = (size_t)((b_ * 16 + h) * 1024);
#pragma unroll
      for (int nc = 0; nc < 2; ++nc) {
        int f = nc * 16 + c;
        float b1_ = bias[ez0 + f], b2_ = bias[ez0 + f + 32];
#pragma unroll
        for (int r = 0; r < 4; ++r) {
          int s = sbase + r;
          float2 cs = rt[s * 32 + f];
          float q1 = acc[fr][nc][r] + b1_;
          float q2 = acc[fr][nc + 2][r] + b2_;
          Qh[(obase + s) * 64 + f] = (bf16_t)((q1 * cs.x - q2 * cs.y) * scl);
          Qh[(obase + s) * 64 + f + 32] = (bf16_t)((q1 * cs.y + q2 * cs.x) * scl);
        }
      }
    }
  } else {
    // K -> granule with rope (see R12 ledger).
#pragma unroll
    for (int fr = 0; fr < 4; ++fr) {
      int i = i0 + wm * 64 + fr * 16 + hi * 4;
      int b_ = i >> 10, sbase = i & 1023;
      bf16_t* gb = Kg + (size_t)((b_ * 16 + h) * 64 + (sbase >> 4)) * 1024;
#pragma unroll
      for (int nc = 0; nc < 2; ++nc) {
        int f = nc * 16 + c;
        float b1_ = bias[ez0 + f], b2_ = bias[ez0 + f + 32];
        int laneHi = (nc * 2 + (c >> 3)) << 4;
#pragma unroll
        for (int r = 0; r < 4; ++r) {
          int s = sbase + r;
          float2 cs = rt[s * 32 + f];
          float q1 = acc[fr][nc][r] + b1_;
          float q2 = acc[fr][nc + 2][r] + b2_;
          size_t off = (size_t)((hi * 4 + r) | laneHi) * 8 + (c & 7);
          gb[off] = (bf16_t)(q1 * cs.x - q2 * cs.y);
          gb[off + 512] = (bf16_t)(q1 * cs.y + q2 * cs.x);
        }
      }
    }
  }
}

// ---------------- out projection: 256 blocks, XCD-chunked [R11] -----------
__global__ __launch_bounds__(512) void k_gemm_out(
    const bf16_t* __restrict__ Ogf, const bf16_t* __restrict__ Wf,
    const float* __restrict__ bo, float* __restrict__ out) {
  const int bid = blockIdx.x;
  const int x = bid & 7, q = bid >> 3;           // q in [0,32)
  const int i0 = (x * 8 + (q & 7)) * 128;
  const int e0 = (q >> 3) * 256;
  const bf16_t* WfO = Wf + (size_t)192 * 16384;

  GEMM_DIRECT_BODY(Ogf, WfO)

#pragma unroll
  for (int fr = 0; fr < 4; ++fr) {
    int i = i0 + wm * 64 + fr * 16 + hi * 4;
#pragma unroll
    for (int nc = 0; nc < 4; ++nc) {
      int e = e0 + wn * 64 + nc * 16 + c;
      float bv_ = bo[e];
#pragma unroll
      for (int r = 0; r < 4; ++r)
        out[(size_t)(i + r) * 1024 + e] = acc[fr][nc][r] + bv_;
    }
  }
}

// ---------------- flash attention (R13: barrier-free, 4 q-sets/wave) ------
// 256 blocks x 512 thr (1 exact round). XCD x owns bh [16x,16x+16) (K+V 4MB
// = L2). Wave = 64 q-rows (4 sets of 16) -> every K/V fragment read feeds 4
// MFMAs (L2 traffic halved vs R12). Sets processed sequentially per tile
// (st live-range 16 VGPR). K double-buffered; V loaded at tile top.
__global__ __launch_bounds__(512) void k_attn(
    const bf16_t* __restrict__ Qh, const bf16_t* __restrict__ Kg,
    const bf16_t* __restrict__ Vg, bf16_t* __restrict__ Ogf) {
  __shared__ alignas(16) char PL[8][2048];
  const int t = threadIdx.x;
  const int lane = t & 63, w = t >> 6;
  const int hi = lane >> 4, c = lane & 15;
  const int bid = blockIdx.x;
  const int wg = (bid & 7) * 32 + (bid >> 3);    // XCD x -> bh [16x,16x+16)
  const int bh = wg >> 1, half = wg & 1;
  const int q0 = half * 512 + w * 64;
  const size_t qbase = (size_t)bh * 64 * 1024;

  const bf16_t* Kb = Kg + (size_t)bh * 65536 + lane * 8;
  const bf16_t* Vb = Vg + (size_t)bh * 65536 + lane * 8;

  bf16x8 qf[4][2];
#pragma unroll
  for (int ss = 0; ss < 4; ++ss)
#pragma unroll
    for (int kk = 0; kk < 2; ++kk)
      qf[ss][kk] = *(const bf16x8*)&Qh[qbase + (size_t)(q0 + ss * 16 + c) * 64 +
                                       kk * 32 + hi * 8];

  f32x4 o[4][4] = {};
  float m_[4] = {-1e30f, -1e30f, -1e30f, -1e30f};
  float l_[4] = {0.f, 0.f, 0.f, 0.f};
  char* const plw = &PL[w][0];

  bf16x8 kp[8], kq[8], vv[8];
#pragma unroll
  for (int i = 0; i < 8; ++i) kp[i] = *(const bf16x8*)(Kb + i * 512);

#define SM_PV(ST, M, L, O)                                                     \
  {                                                                            \
    float pmax = -1e30f;                                                       \
    _Pragma("unroll") for (int ni = 0; ni < 4; ++ni)                           \
      _Pragma("unroll") for (int r = 0; r < 4; ++r)                            \
        pmax = fmaxf(pmax, ST[ni][r]);                                         \
    pmax = fmaxf(pmax, __shfl_xor(pmax, 16));                                  \
    pmax = fmaxf(pmax, __shfl_xor(pmax, 32));                                  \
    float mn = fmaxf(M, pmax);                                                 \
    float scale = EXP2F(M - mn);                                               \
    M = mn;                                                                    \
    float psum = 0.f;                                                          \
    _Pragma("unroll") for (int ni = 0; ni < 4; ++ni) {                         \
      union { bf16_t b[4]; } pk;                                               \
      _Pragma("unroll") for (int r = 0; r < 4; ++r) {                          \
        float p = EXP2F(ST[ni][r] - mn);                                       \
        psum += p;                                                             \
        pk.b[r] = (bf16_t)p;                                                   \
      }                                                                        \
      __builtin_memcpy(plw + (ni * 2 + (hi >> 1)) * 256 + c * 16 + (hi & 1) * 8, \
                       pk.b, 8);                                               \
    }                                                                          \
    psum += __shfl_xor(psum, 16);                                              \
    psum += __shfl_xor(psum, 32);                                              \
    L = L * scale + psum;                                                      \
    _Pragma("unroll") for (int od = 0; od < 4; ++od)                           \
      _Pragma("unroll") for (int r = 0; r < 4; ++r) O[od][r] *= scale;         \
    bf16x8 pa[2];                                                              \
    __builtin_memcpy(&pa[0], plw + lane * 16, 16);                             \
    __builtin_memcpy(&pa[1], plw + 1024 + lane * 16, 16);                      \
    _Pragma("unroll") for (int od = 0; od < 4; ++od)                           \
      _Pragma("unroll") for (int kk = 0; kk < 2; ++kk)                         \
        O[od] = mfma16(vv[od * 2 + kk], pa[kk], O[od]);                        \
  }

#define ATTN_TILE(KS, KN, KT)                                                  \
  {                                                                            \
    _Pragma("unroll") for (int i = 0; i < 8; ++i)                              \
      vv[i] = *(const bf16x8*)(Vb + ((i >> 1) * 32 + (KT) * 2 + (i & 1)) * 512); \
    _Pragma("unroll") for (int ss = 0; ss < 4; ++ss) {                         \
      f32x4 st[4] = {};                                                        \
      _Pragma("unroll") for (int ni = 0; ni < 4; ++ni)                         \
        _Pragma("unroll") for (int kk = 0; kk < 2; ++kk)                       \
          st[ni] = mfma16(KS[ni * 2 + kk], qf[ss][kk], st[ni]);                \
      if (ss == 0 && (KT) + 1 < 16) {                                          \
        _Pragma("unroll") for (int i = 0; i < 8; ++i)                          \
          KN[i] = *(const bf16x8*)(Kb + (((KT) + 1) * 8 + i) * 512);           \
      }                                                                        \
      SM_PV(st, m_[ss], l_[ss], o[ss])                                         \
    }                                                                          \
  }

  for (int jj = 0; jj < 8; ++jj) {
    ATTN_TILE(kp, kq, jj * 2);
    ATTN_TILE(kq, kp, jj * 2 + 1);
  }
#undef ATTN_TILE
#undef SM_PV

  // Epilogue -> Ogf granule layout (4 sets; set ss occupies rowgroup rg0+ss).
  int b_ = bh >> 4, h = bh & 15;
  int rg0 = ((b_ << 10) + q0) >> 4;
#pragma unroll
  for (int ss = 0; ss < 4; ++ss) {
    float iv = 1.f / l_[ss];
#pragma unroll
    for (int od = 0; od < 4; ++od) {
      union { bf16_t b[4]; } pk;
#pragma unroll
      for (int r = 0; r < 4; ++r) pk.b[r] = (bf16_t)(o[ss][od][r] * iv);
      int kt2 = (h << 1) + (od >> 1);
      int lp = ((od & 1) * 2 + (hi >> 1)) * 16 + c;
      int el = (hi & 1) * 4;
      __builtin_memcpy(&Ogf[((size_t)((rg0 + ss) * 32 + kt2) * 64 + lp) * 8 + el],
                       pk.b, 8);
    }
  }
}

extern "C" void kernel_launch(void* const* d_in, const int* in_sizes, int n_in,
                              void* d_out, int out_size, void* d_ws, size_t ws_size,
                              hipStream_t stream) {
  const float* x = (const float*)d_in[0];
  const int* pos = (const int*)d_in[1];
  const float* Wq = (const float*)d_in[2];
  const float* bq = (const float*)d_in[3];
  const float* Wk = (const float*)d_in[4];
  const float* bk = (const float*)d_in[5];
  const float* Wv = (const float*)d_in[6];
  const float* bv = (const float*)d_in[7];
  const float* Wo = (const float*)d_in[8];
  const float* bo = (const float*)d_in[9];
  float* out = (float*)d_out;

  // ws: [0,16M) Xf (granule; reused as Ogf) | [16M,24M) Wf (granule)
  //     [24M,40M) Vg (V^T granule) | [42M,..) rope table.
  // Qh (row-major) + Kg (granule) live in d_out (16MB each).
  char* ws = (char*)d_ws;
  bf16_t* Xf = (bf16_t*)ws;
  bf16_t* Wf = (bf16_t*)(ws + (16u << 20));
  bf16_t* Vg = (bf16_t*)(ws + (24u << 20));
  float2* rt = (float2*)(ws + (42u << 20));
  bf16_t* Qh = (bf16_t*)d_out;
  bf16_t* Kg = (bf16_t*)d_out + (size_t)8 * 1024 * 1024;
  bf16_t* Ogf = Xf;

  k_prep<<<6272, 256, 0, stream>>>(x, Wq, Wk, Wv, Wo, pos, Xf, Wf, rt);
  k_gemm_qkv<<<768, 512, 0, stream>>>(Xf, Wf, bq, bk, bv, rt, Qh, Kg, Vg);
  k_attn<<<256, 512, 0, stream>>>(Qh, Kg, Vg, Ogf);
  k_gemm_out<<<256, 512, 0, stream>>>(Ogf, Wf, bo, out);
}